// Round 12
// baseline (767.392 us; speedup 1.0000x reference)
//
#include <hip/hip_runtime.h>

// ---------------------------------------------------------------------------
// AttDual round 11: GEMM reverted to r9's best (A ring-3 + B single, counted
// vmcnt(4), single-barrier phases). V never materialized: k_bpartv reads the
// pre-LN V-half of HbVQ and applies bias+LN+GELU inline (fp32 V), ln_vq
// shrinks to a Q-half logits kernel.
// ---------------------------------------------------------------------------

typedef unsigned short u16;
typedef __attribute__((ext_vector_type(8))) short          bf16x8;
typedef __attribute__((ext_vector_type(8))) unsigned short u16x8;
typedef __attribute__((ext_vector_type(4))) unsigned short u16x4;
typedef __attribute__((ext_vector_type(4))) float          f32x4;

#define DDIM  1024
#define NROWS 50000
#define MP    50176      // 196 * 256 padded rows (zeros)
#define NCLS  7
#define MPD4  12544      // MP/4

__device__ __forceinline__ u16 f2bf(float f) {          // RNE fp32 -> bf16
  unsigned u = __float_as_uint(f);
  u = (u + 0x7FFFu + ((u >> 16) & 1u)) >> 16;
  return (u16)u;
}
__device__ __forceinline__ float bf2f(u16 h) {
  return __uint_as_float(((unsigned)h) << 16);
}
__device__ __forceinline__ float gelu(float x) {
  return 0.5f * x * (1.0f + erff(x * 0.70710678118654752f));
}

__device__ __forceinline__ void load16_lds(const u16* g, u16* l) {
  __builtin_amdgcn_global_load_lds(
      (const __attribute__((address_space(1))) unsigned int*)(const void*)g,
      (__attribute__((address_space(3))) unsigned int*)(void*)l, 16, 0, 0);
}

#define MFMA_(a, b, c) __builtin_amdgcn_mfma_f32_16x16x32_bf16(a, b, c, 0, 0, 0)

// ------------------------- fp32 -> bf16 convert (features, +row zero-pad) --
__global__ __launch_bounds__(256) void k_convert(const float* __restrict__ src,
                                                 u16* __restrict__ dst,
                                                 int rows_total, int rows_valid) {
  const size_t total = (size_t)rows_total * DDIM / 8;
  const size_t stride = (size_t)gridDim.x * blockDim.x;
  for (size_t i = (size_t)blockIdx.x * blockDim.x + threadIdx.x; i < total; i += stride) {
    const size_t e = i * 8;
    const int row = (int)(e >> 10);
    u16x8 o = {0, 0, 0, 0, 0, 0, 0, 0};
    if (row < rows_valid) {
      const float4* p = (const float4*)(src + e);
      float4 f0 = p[0], f1 = p[1];
      o[0] = f2bf(f0.x); o[1] = f2bf(f0.y); o[2] = f2bf(f0.z); o[3] = f2bf(f0.w);
      o[4] = f2bf(f1.x); o[5] = f2bf(f1.y); o[6] = f2bf(f1.z); o[7] = f2bf(f1.w);
    }
    *(u16x8*)(dst + e) = o;
  }
}

// ------------------------- 3 weight matrices -> Wk, Wvq=concat(Wv,Wq) ------
__global__ __launch_bounds__(256) void k_convw(const float* __restrict__ kw,
                                               const float* __restrict__ vw,
                                               const float* __restrict__ qw,
                                               u16* __restrict__ Wk,
                                               u16* __restrict__ Wvq) {
  const int w = blockIdx.x >> 7;
  const int b = blockIdx.x & 127;
  const float* src = (w == 0) ? kw : (w == 1) ? vw : qw;
  u16* dst = (w == 0) ? Wk : (Wvq + (size_t)(w - 1) * DDIM * DDIM);
  for (int i = b * 256 + threadIdx.x; i < DDIM * DDIM / 8; i += 128 * 256) {
    const float4* p = (const float4*)(src + (size_t)i * 8);
    float4 f0 = p[0], f1 = p[1];
    u16x8 o;
    o[0] = f2bf(f0.x); o[1] = f2bf(f0.y); o[2] = f2bf(f0.z); o[3] = f2bf(f0.w);
    o[4] = f2bf(f1.x); o[5] = f2bf(f1.y); o[6] = f2bf(f1.z); o[7] = f2bf(f1.w);
    *(u16x8*)(dst + (size_t)i * 8) = o;
  }
}

// ------------------------- 256^2 phased GEMM (r9 version, best measured) ---
// C[m,n] = sum_k A[m,k]*B[n,k].  M = 196 tiles; N-tiles = 1<<lnn; ldc given.
// LDS: A ring-3 (96 KiB) + B single (32 KiB). 4 single-barrier phases/tile;
// counted vmcnt(4) at the tile boundary (A(kt+2) stays in flight).
__global__ __launch_bounds__(512, 2) void k_gemm256(const u16* __restrict__ A,
                                                    const u16* __restrict__ Bw,
                                                    u16* __restrict__ C,
                                                    int lnn, int ldc) {
  extern __shared__ __align__(16) u16 smem[];
  u16* Abase = smem;                 // [3][2][8192]
  u16* Bbase = smem + 49152;         // [2][8192]
  const int tid  = threadIdx.x;
  const int lane = tid & 63;
  const int wid  = tid >> 6;
  const int wr = wid >> 2;
  const int wc = wid & 3;
  const int bh = wc >> 1;
  const int bl = (wc & 1) * 64;
  const int fr = lane & 15;
  const int T  = lane >> 4;
  const int cpx = gridDim.x >> 3;                              // nwg % 8 == 0
  const int v  = (blockIdx.x & 7) * cpx + (blockIdx.x >> 3);
  const int m0 = (v >> lnn) * 256;
  const int n0 = (v & ((1 << lnn) - 1)) * 256;

  f32x4 acc[8][4] = {};

#define STAGE_A(KT, BB) do {                                                   \
    _Pragma("unroll") for (int h_ = 0; h_ < 2; ++h_)                           \
      _Pragma("unroll") for (int l_ = 0; l_ < 2; ++l_) {                       \
        const int s_ = l_ * 512 + tid;                                         \
        const int r_ = s_ >> 3;                                                \
        const int c_ = (s_ & 7) ^ (r_ & 7);                                    \
        load16_lds(A + (size_t)(m0 + h_ * 128 + r_) * DDIM + (KT) * 64 + c_ * 8, \
                   Abase + (BB) * 16384 + h_ * 8192 + s_ * 8);                 \
      } } while (0)

#define STAGE_B(KT) do {                                                       \
    _Pragma("unroll") for (int h_ = 0; h_ < 2; ++h_)                           \
      _Pragma("unroll") for (int l_ = 0; l_ < 2; ++l_) {                       \
        const int s_ = l_ * 512 + tid;                                         \
        const int r_ = s_ >> 3;                                                \
        const int c_ = (s_ & 7) ^ (r_ & 7);                                    \
        load16_lds(Bw + (size_t)(n0 + h_ * 128 + r_) * DDIM + (KT) * 64 + c_ * 8, \
                   Bbase + h_ * 8192 + s_ * 8);                                \
      } } while (0)

#define PHASE_A(p) do {                                                        \
    bf16x8 afr[4];                                                             \
    _Pragma("unroll") for (int ks = 0; ks < 2; ++ks)                           \
      _Pragma("unroll") for (int ii = 0; ii < 2; ++ii) {                       \
        const int R = ((p) * 2 + ii) * 16 + fr;                                \
        afr[ks * 2 + ii] = *(const bf16x8*)&Ap[R * 64 + (((ks * 4 + T) ^ (R & 7)) << 3)]; \
      }                                                                        \
    __builtin_amdgcn_s_setprio(1);                                             \
    _Pragma("unroll") for (int ks = 0; ks < 2; ++ks)                           \
      _Pragma("unroll") for (int ii = 0; ii < 2; ++ii)                         \
        _Pragma("unroll") for (int j = 0; j < 4; ++j)                          \
          acc[(p) * 2 + ii][j] = MFMA_(afr[ks * 2 + ii], bfr[ks * 4 + j],      \
                                       acc[(p) * 2 + ii][j]);                  \
    __builtin_amdgcn_s_setprio(0);                                             \
  } while (0)

#define BARP() asm volatile("s_barrier" ::: "memory")

  // prologue: A(0)->slot0, B(0), A(1)->slot1 LAST; counted wait leaves A(1)
  STAGE_A(0, 0);
  STAGE_B(0);
  STAGE_A(1, 1);
  asm volatile("s_waitcnt vmcnt(4)\n\ts_barrier" ::: "memory");

  for (int kt = 0; kt < 16; ++kt) {
    const u16* Ap = Abase + (kt % 3) * 16384 + wr * 8192;
    const u16* Bp = Bbase + bh * 8192;
    bf16x8 bfr[8];
    // PH1: read all B-frags (B buffer dead afterwards) + A rows 0-1
#pragma unroll
    for (int ks = 0; ks < 2; ++ks)
#pragma unroll
      for (int j = 0; j < 4; ++j) {
        const int R = bl + j * 16 + fr;
        bfr[ks * 4 + j] = *(const bf16x8*)&Bp[R * 64 + (((ks * 4 + T) ^ (R & 7)) << 3)];
      }
    PHASE_A(0);
    BARP();
    // PH2: restage the single B buffer with B(kt+1)
    if (kt < 15) STAGE_B(kt + 1);
    PHASE_A(1);
    BARP();
    // PH3: stage A(kt+2) into ring slot (kt+2)%3 (dead since iter kt-1)
    if (kt < 14) STAGE_A(kt + 2, (kt + 2) % 3);
    PHASE_A(2);
    BARP();
    // PH4: counted wait — drain A(kt+1)+B(kt+1), leave A(kt+2) in flight
    PHASE_A(3);
    if (kt < 14)
      asm volatile("s_waitcnt vmcnt(4)\n\ts_barrier" ::: "memory");
    else if (kt == 14)
      asm volatile("s_waitcnt vmcnt(0)\n\ts_barrier" ::: "memory");
  }
#undef STAGE_A
#undef STAGE_B
#undef PHASE_A
#undef BARP

  // epilogue: C write
#pragma unroll
  for (int i = 0; i < 8; ++i)
#pragma unroll
    for (int j = 0; j < 4; ++j) {
      const size_t base = (size_t)(m0 + wr * 128 + i * 16 + T * 4) * ldc
                        + (n0 + wc * 64 + j * 16 + fr);
#pragma unroll
      for (int r = 0; r < 4; ++r)
        C[base + (size_t)r * ldc] = f2bf(acc[i][j][r]);
    }
}

// ------------------------- bias + LN + GELU for K (zero-pads rows) ---------
__global__ __launch_bounds__(256) void k_ln_k(const u16* __restrict__ h,
                                              const float* __restrict__ bias,
                                              const float* __restrict__ g,
                                              const float* __restrict__ beta,
                                              u16* __restrict__ out) {
  const int lane = threadIdx.x & 63;
  const int row = blockIdx.x * 4 + (threadIdx.x >> 6);
  const int c0 = lane * 8;
  u16x8* op0 = (u16x8*)(out + (size_t)row * DDIM + c0);
  u16x8* op1 = (u16x8*)(out + (size_t)row * DDIM + 512 + c0);
  if (row >= NROWS) {
    u16x8 z = {0, 0, 0, 0, 0, 0, 0, 0};
    *op0 = z; *op1 = z;
    return;
  }
  u16x8 h0 = *(const u16x8*)(h + (size_t)row * DDIM + c0);
  u16x8 h1 = *(const u16x8*)(h + (size_t)row * DDIM + 512 + c0);
  float4 a0 = *(const float4*)(bias + c0), a1 = *(const float4*)(bias + c0 + 4);
  float4 a2 = *(const float4*)(bias + 512 + c0), a3 = *(const float4*)(bias + 512 + c0 + 4);
  const float ba[8] = {a0.x, a0.y, a0.z, a0.w, a1.x, a1.y, a1.z, a1.w};
  const float bb[8] = {a2.x, a2.y, a2.z, a2.w, a3.x, a3.y, a3.z, a3.w};
  float v0[8], v1[8];
  float s1 = 0.f, s2 = 0.f;
#pragma unroll
  for (int e = 0; e < 8; ++e) {
    v0[e] = bf2f(h0[e]) + ba[e];
    v1[e] = bf2f(h1[e]) + bb[e];
    s1 += v0[e] + v1[e];
    s2 += v0[e] * v0[e] + v1[e] * v1[e];
  }
#pragma unroll
  for (int m = 1; m < 64; m <<= 1) {
    s1 += __shfl_xor(s1, m, 64);
    s2 += __shfl_xor(s2, m, 64);
  }
  const float mu = s1 * (1.0f / 1024.0f);
  const float var = s2 * (1.0f / 1024.0f) - mu * mu;
  const float rs = rsqrtf(var + 1e-5f);
  float4 g0 = *(const float4*)(g + c0), g1 = *(const float4*)(g + c0 + 4);
  float4 g2 = *(const float4*)(g + 512 + c0), g3 = *(const float4*)(g + 512 + c0 + 4);
  float4 t0 = *(const float4*)(beta + c0), t1 = *(const float4*)(beta + c0 + 4);
  float4 t2 = *(const float4*)(beta + 512 + c0), t3 = *(const float4*)(beta + 512 + c0 + 4);
  const float ga[8] = {g0.x, g0.y, g0.z, g0.w, g1.x, g1.y, g1.z, g1.w};
  const float gb[8] = {g2.x, g2.y, g2.z, g2.w, g3.x, g3.y, g3.z, g3.w};
  const float ta[8] = {t0.x, t0.y, t0.z, t0.w, t1.x, t1.y, t1.z, t1.w};
  const float tb[8] = {t2.x, t2.y, t2.z, t2.w, t3.x, t3.y, t3.z, t3.w};
  u16x8 o0, o1;
#pragma unroll
  for (int e = 0; e < 8; ++e) {
    o0[e] = f2bf(gelu((v0[e] - mu) * rs * ga[e] + ta[e]));
    o1[e] = f2bf(gelu((v1[e] - mu) * rs * gb[e] + tb[e]));
  }
  *op0 = o0; *op1 = o1;
}

// ------------------------- q_max from HbVQ rows (fin of argmax inside) -----
__global__ __launch_bounds__(64) void k_qmax2(const float* __restrict__ argv,
                                              const int* __restrict__ argi,
                                              const u16* __restrict__ hvq,
                                              const float* __restrict__ qb,
                                              const float* __restrict__ qg,
                                              const float* __restrict__ qbeta,
                                              u16* __restrict__ qm) {
  const int j = blockIdx.x;
  const int lane = threadIdx.x;
  float bv = -3.4e38f; int bi = 0x7fffffff;
  for (int p = lane; p < 128; p += 64) {
    const float v = argv[p * NCLS + j];
    const int   i = argi[p * NCLS + j];
    if (v > bv || (v == bv && i < bi)) { bv = v; bi = i; }
  }
#pragma unroll
  for (int m = 1; m < 64; m <<= 1) {
    const float ov = __shfl_xor(bv, m, 64);
    const int   oi = __shfl_xor(bi, m, 64);
    if (ov > bv || (ov == bv && oi < bi)) { bv = ov; bi = oi; }
  }
  const int row = bi;
  const int c0 = lane * 8;
  const u16* hp = hvq + (size_t)row * 2048 + DDIM;      // Q-half
  u16x8 h0 = *(const u16x8*)(hp + c0);
  u16x8 h1 = *(const u16x8*)(hp + 512 + c0);
  float v0[8], v1[8];
  float s1 = 0.f, s2 = 0.f;
#pragma unroll
  for (int e = 0; e < 8; ++e) {
    v0[e] = bf2f(h0[e]) + qb[c0 + e];
    v1[e] = bf2f(h1[e]) + qb[512 + c0 + e];
    s1 += v0[e] + v1[e];
    s2 += v0[e] * v0[e] + v1[e] * v1[e];
  }
#pragma unroll
  for (int m = 1; m < 64; m <<= 1) {
    s1 += __shfl_xor(s1, m, 64);
    s2 += __shfl_xor(s2, m, 64);
  }
  const float mu = s1 * (1.0f / 1024.0f);
  const float var = s2 * (1.0f / 1024.0f) - mu * mu;
  const float rs = rsqrtf(var + 1e-5f);
  u16x8 o0, o1;
#pragma unroll
  for (int e = 0; e < 8; ++e) {
    o0[e] = f2bf(gelu((v0[e] - mu) * rs * qg[c0 + e] + qbeta[c0 + e]));
    o1[e] = f2bf(gelu((v1[e] - mu) * rs * qg[512 + c0 + e] + qbeta[512 + c0 + e]));
  }
  *(u16x8*)(qm + (size_t)j * DDIM + c0) = o0;
  *(u16x8*)(qm + (size_t)j * DDIM + 512 + c0) = o1;
}

// ------------------------- Q-half LN -> logits only ------------------------
__global__ __launch_bounds__(256) void k_ln_q(const u16* __restrict__ h,
                                              const float* __restrict__ q_b,
                                              const float* __restrict__ q_g,
                                              const float* __restrict__ q_beta,
                                              const u16* __restrict__ qm,
                                              float* __restrict__ logits) {
  __shared__ __align__(16) u16 sqm[NCLS * DDIM];        // 14 KB
  const int tid = threadIdx.x;
  const int lane = tid & 63;
  const int row = blockIdx.x * 4 + (tid >> 6);
  for (int i = tid; i < NCLS * DDIM / 8; i += 256)
    *(u16x8*)&sqm[i * 8] = *(const u16x8*)&qm[i * 8];
  __syncthreads();
  if (row >= NROWS) return;
  const int c0 = lane * 8;
  const u16* hp = h + (size_t)row * 2048 + DDIM;        // Q-half
  u16x8 h0 = *(const u16x8*)(hp + c0);
  u16x8 h1 = *(const u16x8*)(hp + 512 + c0);
  float4 a0 = *(const float4*)(q_b + c0), a1 = *(const float4*)(q_b + c0 + 4);
  float4 a2 = *(const float4*)(q_b + 512 + c0), a3 = *(const float4*)(q_b + 512 + c0 + 4);
  const float ba[8] = {a0.x, a0.y, a0.z, a0.w, a1.x, a1.y, a1.z, a1.w};
  const float bb[8] = {a2.x, a2.y, a2.z, a2.w, a3.x, a3.y, a3.z, a3.w};
  float v0[8], v1[8];
  float s1 = 0.f, s2 = 0.f;
#pragma unroll
  for (int e = 0; e < 8; ++e) {
    v0[e] = bf2f(h0[e]) + ba[e];
    v1[e] = bf2f(h1[e]) + bb[e];
    s1 += v0[e] + v1[e];
    s2 += v0[e] * v0[e] + v1[e] * v1[e];
  }
#pragma unroll
  for (int m = 1; m < 64; m <<= 1) {
    s1 += __shfl_xor(s1, m, 64);
    s2 += __shfl_xor(s2, m, 64);
  }
  const float mu = s1 * (1.0f / 1024.0f);
  const float var = s2 * (1.0f / 1024.0f) - mu * mu;
  const float rs = rsqrtf(var + 1e-5f);
  float4 g0 = *(const float4*)(q_g + c0), g1 = *(const float4*)(q_g + c0 + 4);
  float4 g2 = *(const float4*)(q_g + 512 + c0), g3 = *(const float4*)(q_g + 512 + c0 + 4);
  float4 t0 = *(const float4*)(q_beta + c0), t1 = *(const float4*)(q_beta + c0 + 4);
  float4 t2 = *(const float4*)(q_beta + 512 + c0), t3 = *(const float4*)(q_beta + 512 + c0 + 4);
  const float ga[8] = {g0.x, g0.y, g0.z, g0.w, g1.x, g1.y, g1.z, g1.w};
  const float gb[8] = {g2.x, g2.y, g2.z, g2.w, g3.x, g3.y, g3.z, g3.w};
  const float ta[8] = {t0.x, t0.y, t0.z, t0.w, t1.x, t1.y, t1.z, t1.w};
  const float tb[8] = {t2.x, t2.y, t2.z, t2.w, t3.x, t3.y, t3.z, t3.w};
  float y0[8], y1[8];
#pragma unroll
  for (int e = 0; e < 8; ++e) {
    y0[e] = gelu((v0[e] - mu) * rs * ga[e] + ta[e]);
    y1[e] = gelu((v1[e] - mu) * rs * gb[e] + tb[e]);
  }
#pragma unroll
  for (int j = 0; j < NCLS; ++j) {
    u16x8 m0 = *(const u16x8*)&sqm[j * DDIM + c0];
    u16x8 m1 = *(const u16x8*)&sqm[j * DDIM + 512 + c0];
    float p = 0.f;
#pragma unroll
    for (int e = 0; e < 8; ++e) p += y0[e] * bf2f(m0[e]) + y1[e] * bf2f(m1[e]);
#pragma unroll
    for (int m = 1; m < 64; m <<= 1) p += __shfl_xor(p, m, 64);
    if (lane == 0) logits[(size_t)row * NCLS + j] = p * 0.03125f;
  }
}

// ------------------------- argmax partials (first-index) -------------------
__global__ __launch_bounds__(256) void k_arg1(const float* __restrict__ c,
                                              float* __restrict__ pv,
                                              int* __restrict__ pi) {
  __shared__ float sv[256 * NCLS];
  __shared__ int   si[256 * NCLS];
  const int t = threadIdx.x;
  float bv[NCLS]; int bi[NCLS];
#pragma unroll
  for (int j = 0; j < NCLS; ++j) { bv[j] = -3.4e38f; bi[j] = 0x7fffffff; }
  for (int n = blockIdx.x * 256 + t; n < NROWS; n += 128 * 256) {
#pragma unroll
    for (int j = 0; j < NCLS; ++j) {
      const float v = c[(size_t)n * NCLS + j];
      if (v > bv[j]) { bv[j] = v; bi[j] = n; }
    }
  }
#pragma unroll
  for (int j = 0; j < NCLS; ++j) { sv[t * NCLS + j] = bv[j]; si[t * NCLS + j] = bi[j]; }
  __syncthreads();
  for (int s = 128; s > 0; s >>= 1) {
    if (t < s) {
#pragma unroll
      for (int j = 0; j < NCLS; ++j) {
        const float v2 = sv[(t + s) * NCLS + j]; const int i2 = si[(t + s) * NCLS + j];
        const float v1 = sv[t * NCLS + j];       const int i1 = si[t * NCLS + j];
        if (v2 > v1 || (v2 == v1 && i2 < i1)) { sv[t * NCLS + j] = v2; si[t * NCLS + j] = i2; }
      }
    }
    __syncthreads();
  }
  if (t < NCLS) { pv[blockIdx.x * NCLS + t] = sv[t]; pi[blockIdx.x * NCLS + t] = si[t]; }
}

// ------------------------- one-pass softmax partials per block -------------
__global__ __launch_bounds__(256) void k_softpart(const float* __restrict__ logits,
                                                  float* __restrict__ Pm,
                                                  float* __restrict__ Ps) {
  __shared__ float sm[256 * NCLS];
  const int t = threadIdx.x;
  float m[NCLS];
#pragma unroll
  for (int j = 0; j < NCLS; ++j) m[j] = -3.4e38f;
  for (int n = blockIdx.x * 256 + t; n < NROWS; n += 128 * 256)
#pragma unroll
    for (int j = 0; j < NCLS; ++j) m[j] = fmaxf(m[j], logits[(size_t)n * NCLS + j]);
#pragma unroll
  for (int j = 0; j < NCLS; ++j) sm[t * NCLS + j] = m[j];
  __syncthreads();
  for (int s = 128; s > 0; s >>= 1) {
    if (t < s)
#pragma unroll
      for (int j = 0; j < NCLS; ++j)
        sm[t * NCLS + j] = fmaxf(sm[t * NCLS + j], sm[(t + s) * NCLS + j]);
    __syncthreads();
  }
  float mloc[NCLS];
#pragma unroll
  for (int j = 0; j < NCLS; ++j) mloc[j] = sm[j];
  __syncthreads();
  float s[NCLS];
#pragma unroll
  for (int j = 0; j < NCLS; ++j) s[j] = 0.f;
  for (int n = blockIdx.x * 256 + t; n < NROWS; n += 128 * 256)
#pragma unroll
    for (int j = 0; j < NCLS; ++j) s[j] += expf(logits[(size_t)n * NCLS + j] - mloc[j]);
#pragma unroll
  for (int j = 0; j < NCLS; ++j) sm[t * NCLS + j] = s[j];
  __syncthreads();
  for (int st = 128; st > 0; st >>= 1) {
    if (t < st)
#pragma unroll
      for (int j = 0; j < NCLS; ++j) sm[t * NCLS + j] += sm[(t + st) * NCLS + j];
    __syncthreads();
  }
  if (t < NCLS) { Pm[blockIdx.x * NCLS + t] = mloc[t]; Ps[blockIdx.x * NCLS + t] = sm[t]; }
}

// ------------------------- B-partials = A^T V with V computed inline -------
// Reads pre-LN V-half of HbVQ; applies bias+LN+GELU per row (fp32), fuses
// A materialization (Aout) and the softmax rescale-fin. 512 blocks x 98 rows,
// 4 waves/block, wave handles rows {w, w+4, ...}; lane owns 16 cols.
__global__ __launch_bounds__(256) void k_bpartv(const float* __restrict__ logits,
                                                const float* __restrict__ Pm,
                                                const float* __restrict__ Ps,
                                                const u16* __restrict__ hvq,
                                                const float* __restrict__ v_b,
                                                const float* __restrict__ v_g,
                                                const float* __restrict__ v_beta,
                                                float* __restrict__ Aout,
                                                float* __restrict__ Pb) {
  __shared__ float sM[NCLS], sR[NCLS];
  __shared__ float smerge[NCLS * DDIM];                 // 28 KB
  const int t = threadIdx.x;
  const int lane = t & 63;
  const int w = t >> 6;
  if (t < NCLS) {
    float M = -3.4e38f;
    for (int b = 0; b < 128; ++b) M = fmaxf(M, Pm[b * NCLS + t]);
    float S = 0.f;
    for (int b = 0; b < 128; ++b) S += Ps[b * NCLS + t] * expf(Pm[b * NCLS + t] - M);
    sM[t] = M; sR[t] = 1.0f / S;
  }
  for (int i = t; i < NCLS * DDIM; i += 256) smerge[i] = 0.f;
  __syncthreads();

  const int c0 = lane * 16;
  float4 b0 = *(const float4*)(v_b + c0),    b1 = *(const float4*)(v_b + c0 + 4);
  float4 b2 = *(const float4*)(v_b + c0 + 8), b3 = *(const float4*)(v_b + c0 + 12);
  const float bb[16] = {b0.x,b0.y,b0.z,b0.w, b1.x,b1.y,b1.z,b1.w,
                        b2.x,b2.y,b2.z,b2.w, b3.x,b3.y,b3.z,b3.w};
  float4 g0 = *(const float4*)(v_g + c0),    g1 = *(const float4*)(v_g + c0 + 4);
  float4 g2 = *(const float4*)(v_g + c0 + 8), g3 = *(const float4*)(v_g + c0 + 12);
  const float gg[16] = {g0.x,g0.y,g0.z,g0.w, g1.x,g1.y,g1.z,g1.w,
                        g2.x,g2.y,g2.z,g2.w, g3.x,g3.y,g3.z,g3.w};
  float4 t0 = *(const float4*)(v_beta + c0),    t1 = *(const float4*)(v_beta + c0 + 4);
  float4 t2 = *(const float4*)(v_beta + c0 + 8), t3 = *(const float4*)(v_beta + c0 + 12);
  const float tt[16] = {t0.x,t0.y,t0.z,t0.w, t1.x,t1.y,t1.z,t1.w,
                        t2.x,t2.y,t2.z,t2.w, t3.x,t3.y,t3.z,t3.w};

  const int n0 = blockIdx.x * 98;
  int cnt = NROWS - n0;
  cnt = cnt < 0 ? 0 : (cnt > 98 ? 98 : cnt);

  float acc[NCLS][16] = {};
  for (int r = w; r < cnt; r += 4) {
    const int n = n0 + r;
    const u16* hp = hvq + (size_t)n * 2048 + c0;        // V-half (cols 0..1023)
    u16x8 h0 = *(const u16x8*)hp;
    u16x8 h1 = *(const u16x8*)(hp + 8);
    float vv[16];
    float s1 = 0.f, s2 = 0.f;
#pragma unroll
    for (int e = 0; e < 8; ++e) {
      vv[e]     = bf2f(h0[e]) + bb[e];
      vv[e + 8] = bf2f(h1[e]) + bb[e + 8];
    }
#pragma unroll
    for (int e = 0; e < 16; ++e) { s1 += vv[e]; s2 += vv[e] * vv[e]; }
#pragma unroll
    for (int m = 1; m < 64; m <<= 1) {
      s1 += __shfl_xor(s1, m, 64);
      s2 += __shfl_xor(s2, m, 64);
    }
    const float mu = s1 * (1.0f / 1024.0f);
    const float var = s2 * (1.0f / 1024.0f) - mu * mu;
    const float rs = rsqrtf(var + 1e-5f);
    float y[16];
#pragma unroll
    for (int e = 0; e < 16; ++e)
      y[e] = gelu((vv[e] - mu) * rs * gg[e] + tt[e]);
    float a[NCLS];
#pragma unroll
    for (int j = 0; j < NCLS; ++j)
      a[j] = expf(logits[(size_t)n * NCLS + j] - sM[j]) * sR[j];
    if (lane < NCLS) {                                  // runtime idx via LDS only
      const float av = expf(logits[(size_t)n * NCLS + lane] - sM[lane]) * sR[lane];
      Aout[(size_t)n * NCLS + lane] = av;
    }
#pragma unroll
    for (int j = 0; j < NCLS; ++j)
#pragma unroll
      for (int e = 0; e < 16; ++e)
        acc[j][e] += a[j] * y[e];
  }

  // merge 4 waves sequentially into smerge
  for (int ww = 0; ww < 4; ++ww) {
    if (w == ww) {
#pragma unroll
      for (int j = 0; j < NCLS; ++j)
#pragma unroll
        for (int e = 0; e < 16; ++e)
          smerge[j * DDIM + c0 + e] += acc[j][e];
    }
    __syncthreads();
  }
  for (int i = t; i < NCLS * DDIM; i += 256)
    Pb[(size_t)blockIdx.x * NCLS * DDIM + i] = smerge[i];
}

__global__ void k_bred(const float* __restrict__ Pb, float* __restrict__ Bout) {
  const int idx = blockIdx.x * 256 + threadIdx.x;
  if (idx >= NCLS * DDIM) return;
  float s = 0.f;
  for (int p = 0; p < 512; ++p) s += Pb[(size_t)p * NCLS * DDIM + idx];
  Bout[idx] = s;
}

// ------------------------- C[o] = <B, head_w[o]> + head_b[o] ---------------
__global__ __launch_bounds__(256) void k_head(const float* __restrict__ Bmat,
                                              const float* __restrict__ hw,
                                              const float* __restrict__ hb,
                                              float* __restrict__ Cout) {
  const int o = blockIdx.x, t = threadIdx.x;
  float p = 0.f;
  for (int idx = t; idx < NCLS * DDIM; idx += 256)
    p += Bmat[idx] * hw[(size_t)o * NCLS * DDIM + idx];
#pragma unroll
  for (int m = 1; m < 64; m <<= 1) p += __shfl_xor(p, m, 64);
  __shared__ float w[4];
  if ((t & 63) == 0) w[t >> 6] = p;
  __syncthreads();
  if (t == 0) Cout[o] = w[0] + w[1] + w[2] + w[3] + hb[o];
}

// ---------------------------------------------------------------------------
extern "C" void kernel_launch(void* const* d_in, const int* in_sizes, int n_in,
                              void* d_out, int out_size, void* d_ws, size_t ws_size,
                              hipStream_t stream) {
  const float* features   = (const float*)d_in[0];
  const float* c_in       = (const float*)d_in[1];
  const float* key_w      = (const float*)d_in[2];
  const float* key_b      = (const float*)d_in[3];
  const float* key_g      = (const float*)d_in[4];
  const float* key_beta   = (const float*)d_in[5];
  const float* query_w    = (const float*)d_in[6];
  const float* query_b    = (const float*)d_in[7];
  const float* query_g    = (const float*)d_in[8];
  const float* query_beta = (const float*)d_in[9];
  const float* value_w    = (const float*)d_in[10];
  const float* value_b    = (const float*)d_in[11];
  const float* value_g    = (const float*)d_in[12];
  const float* value_beta = (const float*)d_in[13];
  const float* head_w     = (const float*)d_in[14];
  const float* head_b     = (const float*)d_in[15];

  char* ws = (char*)d_ws;
  const size_t SZB = (size_t)MP * DDIM * 2;             // 102,760,448 B
  u16* Xb   = (u16*)ws;                                 // [MP,1024] features bf16
  u16* HbK  = (u16*)(ws + SZB);                         // [MP,1024] pre-LN K
  u16* HbVQ = Xb;                                       // [MP,2048] aliases Xb|HbK (both dead)
  u16* Kb   = (u16*)(ws + 2 * SZB);                     // [MP,1024]
  size_t off = 3 * SZB;
  u16* Wk  = (u16*)(ws + off); off += (size_t)DDIM * DDIM * 2;
  u16* Wvq = (u16*)(ws + off); off += (size_t)2 * DDIM * DDIM * 2;
  float* logits = (float*)(ws + off); off += ((size_t)NROWS * NCLS * 4 + 255) & ~(size_t)255;
  float* Pb  = (float*)(ws + off); off += (size_t)512 * NCLS * DDIM * 4;
  u16* qm    = (u16*)(ws + off); off += ((size_t)NCLS * DDIM * 2 + 255) & ~(size_t)255;
  float* Pmax = (float*)(ws + off); off += ((size_t)128 * NCLS * 4 + 255) & ~(size_t)255;
  float* Psum = (float*)(ws + off); off += ((size_t)128 * NCLS * 4 + 255) & ~(size_t)255;
  float* argv = (float*)(ws + off); off += ((size_t)128 * NCLS * 4 + 255) & ~(size_t)255;
  int*   argi = (int*)  (ws + off); off += ((size_t)128 * NCLS * 4 + 255) & ~(size_t)255;

  float* Cout = (float*)d_out;                          // [7]
  float* Aout = Cout + NCLS;                            // [50000,7]
  float* Bout = Aout + (size_t)NROWS * NCLS;            // [7,1024]

  // argmax partials + dtype converts
  k_arg1<<<128, 256, 0, stream>>>(c_in, argv, argi);
  k_convw<<<384, 256, 0, stream>>>(key_w, value_w, query_w, Wk, Wvq);
  k_convert<<<2048, 256, 0, stream>>>(features, Xb, MP, NROWS);

  // K chain: 256^2 phased GEMM (196 x 4 tiles), then LN (zero-pads to MP)
  k_gemm256<<<784, 512, 131072, stream>>>(Xb, Wk, HbK, 2, 1024);
  k_ln_k<<<MPD4, 256, 0, stream>>>(HbK, key_b, key_g, key_beta, Kb);

  // merged V|Q GEMM: 256^2 phased kernel (196 x 8 tiles); HbVQ aliases Xb|HbK
  k_gemm256<<<1568, 512, 131072, stream>>>(Kb, Wvq, HbVQ, 3, 2048);
  k_qmax2<<<NCLS, 64, 0, stream>>>(argv, argi, HbVQ, query_b, query_g, query_beta, qm);
  k_ln_q<<<MPD4, 256, 0, stream>>>(HbVQ, query_b, query_g, query_beta, qm, logits);

  // softmax over axis 0: one-pass partials, rescale-fin in consumer
  k_softpart<<<128, 256, 0, stream>>>(logits, Pmax, Psum);

  // B = A^T V with V computed inline from HbVQ (fp32); A written on the fly
  k_bpartv<<<512, 256, 0, stream>>>(logits, Pmax, Psum, HbVQ,
                                    value_b, value_g, value_beta, Aout, Pb);
  k_bred<<<28, 256, 0, stream>>>(Pb, Bout);
  k_head<<<NCLS, 256, 0, stream>>>(Bout, head_w, head_b, Cout);
}

// Round 13
// 686.039 us; speedup vs baseline: 1.1186x; 1.1186x over previous
//
#include <hip/hip_runtime.h>

// ---------------------------------------------------------------------------
// AttDual round 12: exact r9 pipeline (best measured, 668us) + k_bpart 2-row
// unroll for memory-level parallelism. GEMM: 256^2 A-ring3/B-single counted
// vmcnt(4). Tail: ln_vq (V + logits), bpart (A-write + rescale-fin fused).
// ---------------------------------------------------------------------------

typedef unsigned short u16;
typedef __attribute__((ext_vector_type(8))) short          bf16x8;
typedef __attribute__((ext_vector_type(8))) unsigned short u16x8;
typedef __attribute__((ext_vector_type(4))) unsigned short u16x4;
typedef __attribute__((ext_vector_type(4))) float          f32x4;

#define DDIM  1024
#define NROWS 50000
#define MP    50176      // 196 * 256 padded rows (zeros)
#define NCLS  7
#define MPD4  12544      // MP/4

__device__ __forceinline__ u16 f2bf(float f) {          // RNE fp32 -> bf16
  unsigned u = __float_as_uint(f);
  u = (u + 0x7FFFu + ((u >> 16) & 1u)) >> 16;
  return (u16)u;
}
__device__ __forceinline__ float bf2f(u16 h) {
  return __uint_as_float(((unsigned)h) << 16);
}
__device__ __forceinline__ float gelu(float x) {
  return 0.5f * x * (1.0f + erff(x * 0.70710678118654752f));
}

__device__ __forceinline__ void load16_lds(const u16* g, u16* l) {
  __builtin_amdgcn_global_load_lds(
      (const __attribute__((address_space(1))) unsigned int*)(const void*)g,
      (__attribute__((address_space(3))) unsigned int*)(void*)l, 16, 0, 0);
}

#define MFMA_(a, b, c) __builtin_amdgcn_mfma_f32_16x16x32_bf16(a, b, c, 0, 0, 0)

// ------------------------- fp32 -> bf16 convert (features, +row zero-pad) --
__global__ __launch_bounds__(256) void k_convert(const float* __restrict__ src,
                                                 u16* __restrict__ dst,
                                                 int rows_total, int rows_valid) {
  const size_t total = (size_t)rows_total * DDIM / 8;
  const size_t stride = (size_t)gridDim.x * blockDim.x;
  for (size_t i = (size_t)blockIdx.x * blockDim.x + threadIdx.x; i < total; i += stride) {
    const size_t e = i * 8;
    const int row = (int)(e >> 10);
    u16x8 o = {0, 0, 0, 0, 0, 0, 0, 0};
    if (row < rows_valid) {
      const float4* p = (const float4*)(src + e);
      float4 f0 = p[0], f1 = p[1];
      o[0] = f2bf(f0.x); o[1] = f2bf(f0.y); o[2] = f2bf(f0.z); o[3] = f2bf(f0.w);
      o[4] = f2bf(f1.x); o[5] = f2bf(f1.y); o[6] = f2bf(f1.z); o[7] = f2bf(f1.w);
    }
    *(u16x8*)(dst + e) = o;
  }
}

// ------------------------- 3 weight matrices -> Wk, Wvq=concat(Wv,Wq) ------
__global__ __launch_bounds__(256) void k_convw(const float* __restrict__ kw,
                                               const float* __restrict__ vw,
                                               const float* __restrict__ qw,
                                               u16* __restrict__ Wk,
                                               u16* __restrict__ Wvq) {
  const int w = blockIdx.x >> 7;
  const int b = blockIdx.x & 127;
  const float* src = (w == 0) ? kw : (w == 1) ? vw : qw;
  u16* dst = (w == 0) ? Wk : (Wvq + (size_t)(w - 1) * DDIM * DDIM);
  for (int i = b * 256 + threadIdx.x; i < DDIM * DDIM / 8; i += 128 * 256) {
    const float4* p = (const float4*)(src + (size_t)i * 8);
    float4 f0 = p[0], f1 = p[1];
    u16x8 o;
    o[0] = f2bf(f0.x); o[1] = f2bf(f0.y); o[2] = f2bf(f0.z); o[3] = f2bf(f0.w);
    o[4] = f2bf(f1.x); o[5] = f2bf(f1.y); o[6] = f2bf(f1.z); o[7] = f2bf(f1.w);
    *(u16x8*)(dst + (size_t)i * 8) = o;
  }
}

// ------------------------- 256^2 phased GEMM (r9 version, best measured) ---
__global__ __launch_bounds__(512, 2) void k_gemm256(const u16* __restrict__ A,
                                                    const u16* __restrict__ Bw,
                                                    u16* __restrict__ C,
                                                    int lnn, int ldc) {
  extern __shared__ __align__(16) u16 smem[];
  u16* Abase = smem;                 // [3][2][8192]
  u16* Bbase = smem + 49152;         // [2][8192]
  const int tid  = threadIdx.x;
  const int lane = tid & 63;
  const int wid  = tid >> 6;
  const int wr = wid >> 2;
  const int wc = wid & 3;
  const int bh = wc >> 1;
  const int bl = (wc & 1) * 64;
  const int fr = lane & 15;
  const int T  = lane >> 4;
  const int cpx = gridDim.x >> 3;                              // nwg % 8 == 0
  const int v  = (blockIdx.x & 7) * cpx + (blockIdx.x >> 3);
  const int m0 = (v >> lnn) * 256;
  const int n0 = (v & ((1 << lnn) - 1)) * 256;

  f32x4 acc[8][4] = {};

#define STAGE_A(KT, BB) do {                                                   \
    _Pragma("unroll") for (int h_ = 0; h_ < 2; ++h_)                           \
      _Pragma("unroll") for (int l_ = 0; l_ < 2; ++l_) {                       \
        const int s_ = l_ * 512 + tid;                                         \
        const int r_ = s_ >> 3;                                                \
        const int c_ = (s_ & 7) ^ (r_ & 7);                                    \
        load16_lds(A + (size_t)(m0 + h_ * 128 + r_) * DDIM + (KT) * 64 + c_ * 8, \
                   Abase + (BB) * 16384 + h_ * 8192 + s_ * 8);                 \
      } } while (0)

#define STAGE_B(KT) do {                                                       \
    _Pragma("unroll") for (int h_ = 0; h_ < 2; ++h_)                           \
      _Pragma("unroll") for (int l_ = 0; l_ < 2; ++l_) {                       \
        const int s_ = l_ * 512 + tid;                                         \
        const int r_ = s_ >> 3;                                                \
        const int c_ = (s_ & 7) ^ (r_ & 7);                                    \
        load16_lds(Bw + (size_t)(n0 + h_ * 128 + r_) * DDIM + (KT) * 64 + c_ * 8, \
                   Bbase + h_ * 8192 + s_ * 8);                                \
      } } while (0)

#define PHASE_A(p) do {                                                        \
    bf16x8 afr[4];                                                             \
    _Pragma("unroll") for (int ks = 0; ks < 2; ++ks)                           \
      _Pragma("unroll") for (int ii = 0; ii < 2; ++ii) {                       \
        const int R = ((p) * 2 + ii) * 16 + fr;                                \
        afr[ks * 2 + ii] = *(const bf16x8*)&Ap[R * 64 + (((ks * 4 + T) ^ (R & 7)) << 3)]; \
      }                                                                        \
    __builtin_amdgcn_s_setprio(1);                                             \
    _Pragma("unroll") for (int ks = 0; ks < 2; ++ks)                           \
      _Pragma("unroll") for (int ii = 0; ii < 2; ++ii)                         \
        _Pragma("unroll") for (int j = 0; j < 4; ++j)                          \
          acc[(p) * 2 + ii][j] = MFMA_(afr[ks * 2 + ii], bfr[ks * 4 + j],      \
                                       acc[(p) * 2 + ii][j]);                  \
    __builtin_amdgcn_s_setprio(0);                                             \
  } while (0)

#define BARP() asm volatile("s_barrier" ::: "memory")

  // prologue: A(0)->slot0, B(0), A(1)->slot1 LAST; counted wait leaves A(1)
  STAGE_A(0, 0);
  STAGE_B(0);
  STAGE_A(1, 1);
  asm volatile("s_waitcnt vmcnt(4)\n\ts_barrier" ::: "memory");

  for (int kt = 0; kt < 16; ++kt) {
    const u16* Ap = Abase + (kt % 3) * 16384 + wr * 8192;
    const u16* Bp = Bbase + bh * 8192;
    bf16x8 bfr[8];
    // PH1: read all B-frags (B buffer dead afterwards) + A rows 0-1
#pragma unroll
    for (int ks = 0; ks < 2; ++ks)
#pragma unroll
      for (int j = 0; j < 4; ++j) {
        const int R = bl + j * 16 + fr;
        bfr[ks * 4 + j] = *(const bf16x8*)&Bp[R * 64 + (((ks * 4 + T) ^ (R & 7)) << 3)];
      }
    PHASE_A(0);
    BARP();
    // PH2: restage the single B buffer with B(kt+1)
    if (kt < 15) STAGE_B(kt + 1);
    PHASE_A(1);
    BARP();
    // PH3: stage A(kt+2) into ring slot (kt+2)%3 (dead since iter kt-1)
    if (kt < 14) STAGE_A(kt + 2, (kt + 2) % 3);
    PHASE_A(2);
    BARP();
    // PH4: counted wait — drain A(kt+1)+B(kt+1), leave A(kt+2) in flight
    PHASE_A(3);
    if (kt < 14)
      asm volatile("s_waitcnt vmcnt(4)\n\ts_barrier" ::: "memory");
    else if (kt == 14)
      asm volatile("s_waitcnt vmcnt(0)\n\ts_barrier" ::: "memory");
  }
#undef STAGE_A
#undef STAGE_B
#undef PHASE_A
#undef BARP

  // epilogue: C write
#pragma unroll
  for (int i = 0; i < 8; ++i)
#pragma unroll
    for (int j = 0; j < 4; ++j) {
      const size_t base = (size_t)(m0 + wr * 128 + i * 16 + T * 4) * ldc
                        + (n0 + wc * 64 + j * 16 + fr);
#pragma unroll
      for (int r = 0; r < 4; ++r)
        C[base + (size_t)r * ldc] = f2bf(acc[i][j][r]);
    }
}

// ------------------------- bias + LN + GELU for K (zero-pads rows) ---------
__global__ __launch_bounds__(256) void k_ln_k(const u16* __restrict__ h,
                                              const float* __restrict__ bias,
                                              const float* __restrict__ g,
                                              const float* __restrict__ beta,
                                              u16* __restrict__ out) {
  const int lane = threadIdx.x & 63;
  const int row = blockIdx.x * 4 + (threadIdx.x >> 6);
  const int c0 = lane * 8;
  u16x8* op0 = (u16x8*)(out + (size_t)row * DDIM + c0);
  u16x8* op1 = (u16x8*)(out + (size_t)row * DDIM + 512 + c0);
  if (row >= NROWS) {
    u16x8 z = {0, 0, 0, 0, 0, 0, 0, 0};
    *op0 = z; *op1 = z;
    return;
  }
  u16x8 h0 = *(const u16x8*)(h + (size_t)row * DDIM + c0);
  u16x8 h1 = *(const u16x8*)(h + (size_t)row * DDIM + 512 + c0);
  float4 a0 = *(const float4*)(bias + c0), a1 = *(const float4*)(bias + c0 + 4);
  float4 a2 = *(const float4*)(bias + 512 + c0), a3 = *(const float4*)(bias + 512 + c0 + 4);
  const float ba[8] = {a0.x, a0.y, a0.z, a0.w, a1.x, a1.y, a1.z, a1.w};
  const float bb[8] = {a2.x, a2.y, a2.z, a2.w, a3.x, a3.y, a3.z, a3.w};
  float v0[8], v1[8];
  float s1 = 0.f, s2 = 0.f;
#pragma unroll
  for (int e = 0; e < 8; ++e) {
    v0[e] = bf2f(h0[e]) + ba[e];
    v1[e] = bf2f(h1[e]) + bb[e];
    s1 += v0[e] + v1[e];
    s2 += v0[e] * v0[e] + v1[e] * v1[e];
  }
#pragma unroll
  for (int m = 1; m < 64; m <<= 1) {
    s1 += __shfl_xor(s1, m, 64);
    s2 += __shfl_xor(s2, m, 64);
  }
  const float mu = s1 * (1.0f / 1024.0f);
  const float var = s2 * (1.0f / 1024.0f) - mu * mu;
  const float rs = rsqrtf(var + 1e-5f);
  float4 g0 = *(const float4*)(g + c0), g1 = *(const float4*)(g + c0 + 4);
  float4 g2 = *(const float4*)(g + 512 + c0), g3 = *(const float4*)(g + 512 + c0 + 4);
  float4 t0 = *(const float4*)(beta + c0), t1 = *(const float4*)(beta + c0 + 4);
  float4 t2 = *(const float4*)(beta + 512 + c0), t3 = *(const float4*)(beta + 512 + c0 + 4);
  const float ga[8] = {g0.x, g0.y, g0.z, g0.w, g1.x, g1.y, g1.z, g1.w};
  const float gb[8] = {g2.x, g2.y, g2.z, g2.w, g3.x, g3.y, g3.z, g3.w};
  const float ta[8] = {t0.x, t0.y, t0.z, t0.w, t1.x, t1.y, t1.z, t1.w};
  const float tb[8] = {t2.x, t2.y, t2.z, t2.w, t3.x, t3.y, t3.z, t3.w};
  u16x8 o0, o1;
#pragma unroll
  for (int e = 0; e < 8; ++e) {
    o0[e] = f2bf(gelu((v0[e] - mu) * rs * ga[e] + ta[e]));
    o1[e] = f2bf(gelu((v1[e] - mu) * rs * gb[e] + tb[e]));
  }
  *op0 = o0; *op1 = o1;
}

// ------------------------- q_max from HbVQ rows (fin of argmax inside) -----
__global__ __launch_bounds__(64) void k_qmax2(const float* __restrict__ argv,
                                              const int* __restrict__ argi,
                                              const u16* __restrict__ hvq,
                                              const float* __restrict__ qb,
                                              const float* __restrict__ qg,
                                              const float* __restrict__ qbeta,
                                              u16* __restrict__ qm) {
  const int j = blockIdx.x;
  const int lane = threadIdx.x;
  float bv = -3.4e38f; int bi = 0x7fffffff;
  for (int p = lane; p < 128; p += 64) {
    const float v = argv[p * NCLS + j];
    const int   i = argi[p * NCLS + j];
    if (v > bv || (v == bv && i < bi)) { bv = v; bi = i; }
  }
#pragma unroll
  for (int m = 1; m < 64; m <<= 1) {
    const float ov = __shfl_xor(bv, m, 64);
    const int   oi = __shfl_xor(bi, m, 64);
    if (ov > bv || (ov == bv && oi < bi)) { bv = ov; bi = oi; }
  }
  const int row = bi;
  const int c0 = lane * 8;
  const u16* hp = hvq + (size_t)row * 2048 + DDIM;      // Q-half
  u16x8 h0 = *(const u16x8*)(hp + c0);
  u16x8 h1 = *(const u16x8*)(hp + 512 + c0);
  float v0[8], v1[8];
  float s1 = 0.f, s2 = 0.f;
#pragma unroll
  for (int e = 0; e < 8; ++e) {
    v0[e] = bf2f(h0[e]) + qb[c0 + e];
    v1[e] = bf2f(h1[e]) + qb[512 + c0 + e];
    s1 += v0[e] + v1[e];
    s2 += v0[e] * v0[e] + v1[e] * v1[e];
  }
#pragma unroll
  for (int m = 1; m < 64; m <<= 1) {
    s1 += __shfl_xor(s1, m, 64);
    s2 += __shfl_xor(s2, m, 64);
  }
  const float mu = s1 * (1.0f / 1024.0f);
  const float var = s2 * (1.0f / 1024.0f) - mu * mu;
  const float rs = rsqrtf(var + 1e-5f);
  u16x8 o0, o1;
#pragma unroll
  for (int e = 0; e < 8; ++e) {
    o0[e] = f2bf(gelu((v0[e] - mu) * rs * qg[c0 + e] + qbeta[c0 + e]));
    o1[e] = f2bf(gelu((v1[e] - mu) * rs * qg[512 + c0 + e] + qbeta[512 + c0 + e]));
  }
  *(u16x8*)(qm + (size_t)j * DDIM + c0) = o0;
  *(u16x8*)(qm + (size_t)j * DDIM + 512 + c0) = o1;
}

// ------------------------- merged V/Q LN; Q-half emits logits only ---------
__global__ __launch_bounds__(256) void k_ln_vq(const u16* __restrict__ h,
                                               const float* __restrict__ v_b,
                                               const float* __restrict__ v_g,
                                               const float* __restrict__ v_beta,
                                               const float* __restrict__ q_b,
                                               const float* __restrict__ q_g,
                                               const float* __restrict__ q_beta,
                                               const u16* __restrict__ qm,
                                               u16* __restrict__ V,
                                               float* __restrict__ logits) {
  __shared__ __align__(16) u16 sqm[NCLS * DDIM];        // 14 KB
  const int tid = threadIdx.x;
  const int lane = tid & 63;
  const int half = (blockIdx.x >= MPD4) ? 1 : 0;
  const int rb = half ? (blockIdx.x - MPD4) : blockIdx.x;
  const int row = rb * 4 + (tid >> 6);
  if (half) {
    for (int i = tid; i < NCLS * DDIM / 8; i += 256)
      *(u16x8*)&sqm[i * 8] = *(const u16x8*)&qm[i * 8];
    __syncthreads();
  }
  if (row >= NROWS) return;                             // no sync after this
  const float* bias = half ? q_b : v_b;
  const float* gain = half ? q_g : v_g;
  const float* bet  = half ? q_beta : v_beta;
  const int c0 = lane * 8;
  const u16* hp = h + (size_t)row * 2048 + (size_t)half * DDIM;
  u16x8 h0 = *(const u16x8*)(hp + c0);
  u16x8 h1 = *(const u16x8*)(hp + 512 + c0);
  float4 a0 = *(const float4*)(bias + c0), a1 = *(const float4*)(bias + c0 + 4);
  float4 a2 = *(const float4*)(bias + 512 + c0), a3 = *(const float4*)(bias + 512 + c0 + 4);
  const float ba[8] = {a0.x, a0.y, a0.z, a0.w, a1.x, a1.y, a1.z, a1.w};
  const float bb[8] = {a2.x, a2.y, a2.z, a2.w, a3.x, a3.y, a3.z, a3.w};
  float v0[8], v1[8];
  float s1 = 0.f, s2 = 0.f;
#pragma unroll
  for (int e = 0; e < 8; ++e) {
    v0[e] = bf2f(h0[e]) + ba[e];
    v1[e] = bf2f(h1[e]) + bb[e];
    s1 += v0[e] + v1[e];
    s2 += v0[e] * v0[e] + v1[e] * v1[e];
  }
#pragma unroll
  for (int m = 1; m < 64; m <<= 1) {
    s1 += __shfl_xor(s1, m, 64);
    s2 += __shfl_xor(s2, m, 64);
  }
  const float mu = s1 * (1.0f / 1024.0f);
  const float var = s2 * (1.0f / 1024.0f) - mu * mu;
  const float rs = rsqrtf(var + 1e-5f);
  float4 g0 = *(const float4*)(gain + c0), g1 = *(const float4*)(gain + c0 + 4);
  float4 g2 = *(const float4*)(gain + 512 + c0), g3 = *(const float4*)(gain + 512 + c0 + 4);
  float4 t0 = *(const float4*)(bet + c0), t1 = *(const float4*)(bet + c0 + 4);
  float4 t2 = *(const float4*)(bet + 512 + c0), t3 = *(const float4*)(bet + 512 + c0 + 4);
  const float ga[8] = {g0.x, g0.y, g0.z, g0.w, g1.x, g1.y, g1.z, g1.w};
  const float gb[8] = {g2.x, g2.y, g2.z, g2.w, g3.x, g3.y, g3.z, g3.w};
  const float ta[8] = {t0.x, t0.y, t0.z, t0.w, t1.x, t1.y, t1.z, t1.w};
  const float tb[8] = {t2.x, t2.y, t2.z, t2.w, t3.x, t3.y, t3.z, t3.w};
  float y0[8], y1[8];
#pragma unroll
  for (int e = 0; e < 8; ++e) {
    y0[e] = gelu((v0[e] - mu) * rs * ga[e] + ta[e]);
    y1[e] = gelu((v1[e] - mu) * rs * gb[e] + tb[e]);
  }
  if (half == 0) {
    u16x8 o0, o1;
#pragma unroll
    for (int e = 0; e < 8; ++e) { o0[e] = f2bf(y0[e]); o1[e] = f2bf(y1[e]); }
    *(u16x8*)(V + (size_t)row * DDIM + c0) = o0;
    *(u16x8*)(V + (size_t)row * DDIM + 512 + c0) = o1;
  } else {
#pragma unroll
    for (int j = 0; j < NCLS; ++j) {
      u16x8 m0 = *(const u16x8*)&sqm[j * DDIM + c0];
      u16x8 m1 = *(const u16x8*)&sqm[j * DDIM + 512 + c0];
      float p = 0.f;
#pragma unroll
      for (int e = 0; e < 8; ++e) p += y0[e] * bf2f(m0[e]) + y1[e] * bf2f(m1[e]);
#pragma unroll
      for (int m = 1; m < 64; m <<= 1) p += __shfl_xor(p, m, 64);
      if (lane == 0) logits[(size_t)row * NCLS + j] = p * 0.03125f;
    }
  }
}

// ------------------------- argmax partials (first-index) -------------------
__global__ __launch_bounds__(256) void k_arg1(const float* __restrict__ c,
                                              float* __restrict__ pv,
                                              int* __restrict__ pi) {
  __shared__ float sv[256 * NCLS];
  __shared__ int   si[256 * NCLS];
  const int t = threadIdx.x;
  float bv[NCLS]; int bi[NCLS];
#pragma unroll
  for (int j = 0; j < NCLS; ++j) { bv[j] = -3.4e38f; bi[j] = 0x7fffffff; }
  for (int n = blockIdx.x * 256 + t; n < NROWS; n += 128 * 256) {
#pragma unroll
    for (int j = 0; j < NCLS; ++j) {
      const float v = c[(size_t)n * NCLS + j];
      if (v > bv[j]) { bv[j] = v; bi[j] = n; }
    }
  }
#pragma unroll
  for (int j = 0; j < NCLS; ++j) { sv[t * NCLS + j] = bv[j]; si[t * NCLS + j] = bi[j]; }
  __syncthreads();
  for (int s = 128; s > 0; s >>= 1) {
    if (t < s) {
#pragma unroll
      for (int j = 0; j < NCLS; ++j) {
        const float v2 = sv[(t + s) * NCLS + j]; const int i2 = si[(t + s) * NCLS + j];
        const float v1 = sv[t * NCLS + j];       const int i1 = si[t * NCLS + j];
        if (v2 > v1 || (v2 == v1 && i2 < i1)) { sv[t * NCLS + j] = v2; si[t * NCLS + j] = i2; }
      }
    }
    __syncthreads();
  }
  if (t < NCLS) { pv[blockIdx.x * NCLS + t] = sv[t]; pi[blockIdx.x * NCLS + t] = si[t]; }
}

// ------------------------- one-pass softmax partials per block -------------
__global__ __launch_bounds__(256) void k_softpart(const float* __restrict__ logits,
                                                  float* __restrict__ Pm,
                                                  float* __restrict__ Ps) {
  __shared__ float sm[256 * NCLS];
  const int t = threadIdx.x;
  float m[NCLS];
#pragma unroll
  for (int j = 0; j < NCLS; ++j) m[j] = -3.4e38f;
  for (int n = blockIdx.x * 256 + t; n < NROWS; n += 128 * 256)
#pragma unroll
    for (int j = 0; j < NCLS; ++j) m[j] = fmaxf(m[j], logits[(size_t)n * NCLS + j]);
#pragma unroll
  for (int j = 0; j < NCLS; ++j) sm[t * NCLS + j] = m[j];
  __syncthreads();
  for (int s = 128; s > 0; s >>= 1) {
    if (t < s)
#pragma unroll
      for (int j = 0; j < NCLS; ++j)
        sm[t * NCLS + j] = fmaxf(sm[t * NCLS + j], sm[(t + s) * NCLS + j]);
    __syncthreads();
  }
  float mloc[NCLS];
#pragma unroll
  for (int j = 0; j < NCLS; ++j) mloc[j] = sm[j];
  __syncthreads();
  float s[NCLS];
#pragma unroll
  for (int j = 0; j < NCLS; ++j) s[j] = 0.f;
  for (int n = blockIdx.x * 256 + t; n < NROWS; n += 128 * 256)
#pragma unroll
    for (int j = 0; j < NCLS; ++j) s[j] += expf(logits[(size_t)n * NCLS + j] - mloc[j]);
#pragma unroll
  for (int j = 0; j < NCLS; ++j) sm[t * NCLS + j] = s[j];
  __syncthreads();
  for (int st = 128; st > 0; st >>= 1) {
    if (t < st)
#pragma unroll
      for (int j = 0; j < NCLS; ++j) sm[t * NCLS + j] += sm[(t + st) * NCLS + j];
    __syncthreads();
  }
  if (t < NCLS) { Pm[blockIdx.x * NCLS + t] = mloc[t]; Ps[blockIdx.x * NCLS + t] = sm[t]; }
}

// ------------------------- B-partials = A^T V, fused A-write + rescale-fin -
// 2-row unroll: both V loads issued before the FMA chains (2x MLP).
__global__ __launch_bounds__(256) void k_bpart(const float* __restrict__ logits,
                                               const float* __restrict__ Pm,
                                               const float* __restrict__ Ps,
                                               const u16* __restrict__ V,
                                               float* __restrict__ Aout,
                                               float* __restrict__ Pb) {
  __shared__ float sA[98 * NCLS];
  __shared__ float sM[NCLS], sR[NCLS];
  const int t = threadIdx.x;
  if (t < NCLS) {
    float M = -3.4e38f;
    for (int b = 0; b < 128; ++b) M = fmaxf(M, Pm[b * NCLS + t]);
    float S = 0.f;
    for (int b = 0; b < 128; ++b) S += Ps[b * NCLS + t] * expf(Pm[b * NCLS + t] - M);
    sM[t] = M; sR[t] = 1.0f / S;
  }
  __syncthreads();
  const int n0 = blockIdx.x * 98;
  int cnt = NROWS - n0;
  cnt = cnt < 0 ? 0 : (cnt > 98 ? 98 : cnt);
  for (int idx = t; idx < cnt * NCLS; idx += 256) {
    const int j = idx % NCLS;
    const float a = expf(logits[(size_t)n0 * NCLS + idx] - sM[j]) * sR[j];
    sA[idx] = a;
    Aout[(size_t)n0 * NCLS + idx] = a;
  }
  __syncthreads();
  float acc[NCLS][4] = {};
  int r = 0;
  for (; r + 2 <= cnt; r += 2) {
    u16x4 va = *(const u16x4*)&V[(size_t)(n0 + r) * DDIM + t * 4];
    u16x4 vb = *(const u16x4*)&V[(size_t)(n0 + r + 1) * DDIM + t * 4];
    const float a0 = bf2f(va[0]), a1 = bf2f(va[1]), a2 = bf2f(va[2]), a3 = bf2f(va[3]);
    const float c0 = bf2f(vb[0]), c1 = bf2f(vb[1]), c2 = bf2f(vb[2]), c3 = bf2f(vb[3]);
#pragma unroll
    for (int j = 0; j < NCLS; ++j) {
      const float aj = sA[r * NCLS + j];
      const float bj = sA[(r + 1) * NCLS + j];
      acc[j][0] += aj * a0 + bj * c0;
      acc[j][1] += aj * a1 + bj * c1;
      acc[j][2] += aj * a2 + bj * c2;
      acc[j][3] += aj * a3 + bj * c3;
    }
  }
  if (r < cnt) {
    u16x4 va = *(const u16x4*)&V[(size_t)(n0 + r) * DDIM + t * 4];
    const float a0 = bf2f(va[0]), a1 = bf2f(va[1]), a2 = bf2f(va[2]), a3 = bf2f(va[3]);
#pragma unroll
    for (int j = 0; j < NCLS; ++j) {
      const float aj = sA[r * NCLS + j];
      acc[j][0] += aj * a0; acc[j][1] += aj * a1;
      acc[j][2] += aj * a2; acc[j][3] += aj * a3;
    }
  }
#pragma unroll
  for (int j = 0; j < NCLS; ++j) {
    f32x4 o = {acc[j][0], acc[j][1], acc[j][2], acc[j][3]};
    *(f32x4*)&Pb[((size_t)blockIdx.x * NCLS + j) * DDIM + t * 4] = o;
  }
}

__global__ void k_bred(const float* __restrict__ Pb, float* __restrict__ Bout) {
  const int idx = blockIdx.x * 256 + threadIdx.x;
  if (idx >= NCLS * DDIM) return;
  float s = 0.f;
  for (int p = 0; p < 512; ++p) s += Pb[(size_t)p * NCLS * DDIM + idx];
  Bout[idx] = s;
}

// ------------------------- C[o] = <B, head_w[o]> + head_b[o] ---------------
__global__ __launch_bounds__(256) void k_head(const float* __restrict__ Bmat,
                                              const float* __restrict__ hw,
                                              const float* __restrict__ hb,
                                              float* __restrict__ Cout) {
  const int o = blockIdx.x, t = threadIdx.x;
  float p = 0.f;
  for (int idx = t; idx < NCLS * DDIM; idx += 256)
    p += Bmat[idx] * hw[(size_t)o * NCLS * DDIM + idx];
#pragma unroll
  for (int m = 1; m < 64; m <<= 1) p += __shfl_xor(p, m, 64);
  __shared__ float w[4];
  if ((t & 63) == 0) w[t >> 6] = p;
  __syncthreads();
  if (t == 0) Cout[o] = w[0] + w[1] + w[2] + w[3] + hb[o];
}

// ---------------------------------------------------------------------------
extern "C" void kernel_launch(void* const* d_in, const int* in_sizes, int n_in,
                              void* d_out, int out_size, void* d_ws, size_t ws_size,
                              hipStream_t stream) {
  const float* features   = (const float*)d_in[0];
  const float* c_in       = (const float*)d_in[1];
  const float* key_w      = (const float*)d_in[2];
  const float* key_b      = (const float*)d_in[3];
  const float* key_g      = (const float*)d_in[4];
  const float* key_beta   = (const float*)d_in[5];
  const float* query_w    = (const float*)d_in[6];
  const float* query_b    = (const float*)d_in[7];
  const float* query_g    = (const float*)d_in[8];
  const float* query_beta = (const float*)d_in[9];
  const float* value_w    = (const float*)d_in[10];
  const float* value_b    = (const float*)d_in[11];
  const float* value_g    = (const float*)d_in[12];
  const float* value_beta = (const float*)d_in[13];
  const float* head_w     = (const float*)d_in[14];
  const float* head_b     = (const float*)d_in[15];

  char* ws = (char*)d_ws;
  const size_t SZB = (size_t)MP * DDIM * 2;             // 102,760,448 B
  u16* Xb   = (u16*)ws;                                 // [MP,1024] features bf16
  u16* HbK  = (u16*)(ws + SZB);                         // [MP,1024] pre-LN K
  u16* HbVQ = Xb;                                       // [MP,2048] aliases Xb|HbK (both dead)
  u16* Kb   = (u16*)(ws + 2 * SZB);                     // [MP,1024]
  u16* Vb   = Kb;                                       // reuse after VQ-GEMM
  size_t off = 3 * SZB;
  u16* Wk  = (u16*)(ws + off); off += (size_t)DDIM * DDIM * 2;
  u16* Wvq = (u16*)(ws + off); off += (size_t)2 * DDIM * DDIM * 2;
  float* logits = (float*)(ws + off); off += ((size_t)NROWS * NCLS * 4 + 255) & ~(size_t)255;
  float* Pb  = (float*)(ws + off); off += (size_t)512 * NCLS * DDIM * 4;
  u16* qm    = (u16*)(ws + off); off += ((size_t)NCLS * DDIM * 2 + 255) & ~(size_t)255;
  float* Pmax = (float*)(ws + off); off += ((size_t)128 * NCLS * 4 + 255) & ~(size_t)255;
  float* Psum = (float*)(ws + off); off += ((size_t)128 * NCLS * 4 + 255) & ~(size_t)255;
  float* argv = (float*)(ws + off); off += ((size_t)128 * NCLS * 4 + 255) & ~(size_t)255;
  int*   argi = (int*)  (ws + off); off += ((size_t)128 * NCLS * 4 + 255) & ~(size_t)255;

  float* Cout = (float*)d_out;                          // [7]
  float* Aout = Cout + NCLS;                            // [50000,7]
  float* Bout = Aout + (size_t)NROWS * NCLS;            // [7,1024]

  // argmax partials + dtype converts
  k_arg1<<<128, 256, 0, stream>>>(c_in, argv, argi);
  k_convw<<<384, 256, 0, stream>>>(key_w, value_w, query_w, Wk, Wvq);
  k_convert<<<2048, 256, 0, stream>>>(features, Xb, MP, NROWS);

  // K chain: 256^2 phased GEMM (196 x 4 tiles), then LN (zero-pads to MP)
  k_gemm256<<<784, 512, 131072, stream>>>(Xb, Wk, HbK, 2, 1024);
  k_ln_k<<<MPD4, 256, 0, stream>>>(HbK, key_b, key_g, key_beta, Kb);

  // merged V|Q GEMM: 256^2 phased kernel (196 x 8 tiles); HbVQ aliases Xb|HbK
  k_gemm256<<<1568, 512, 131072, stream>>>(Kb, Wvq, HbVQ, 3, 2048);
  k_qmax2<<<NCLS, 64, 0, stream>>>(argv, argi, HbVQ, query_b, query_g, query_beta, qm);
  k_ln_vq<<<2 * MPD4, 256, 0, stream>>>(HbVQ, value_b, value_g, value_beta,
                                        query_b, query_g, query_beta, qm, Vb, logits);

  // softmax over axis 0: one-pass partials, rescale-fin in consumer
  k_softpart<<<128, 256, 0, stream>>>(logits, Pmax, Psum);

  // B = A^T V (A materialized on the fly), head contraction
  k_bpart<<<512, 256, 0, stream>>>(logits, Pmax, Psum, Vb, Aout, Pb);
  k_bred<<<28, 256, 0, stream>>>(Pb, Bout);
  k_head<<<NCLS, 256, 0, stream>>>(Bout, head_w, head_b, Cout);
}

// Round 14
// 666.161 us; speedup vs baseline: 1.1520x; 1.0298x over previous
//
#include <hip/hip_runtime.h>

// ---------------------------------------------------------------------------
// AttDual FINAL (= round 9, best measured 668us): 256^2/BK=64 phased GEMM
// (A ring-3 + B single, counted vmcnt(4), setprio, conflict-free swizzle,
// XCD-bijective block swizzle) for both K and V|Q chains; fused tail:
// ln_k, qmax-from-HbVQ, ln_vq (V + logits), one-pass softmax partials,
// bpart (A-write + rescale-fin + B-partials), bred, head.
// ---------------------------------------------------------------------------

typedef unsigned short u16;
typedef __attribute__((ext_vector_type(8))) short          bf16x8;
typedef __attribute__((ext_vector_type(8))) unsigned short u16x8;
typedef __attribute__((ext_vector_type(4))) unsigned short u16x4;
typedef __attribute__((ext_vector_type(4))) float          f32x4;

#define DDIM  1024
#define NROWS 50000
#define MP    50176      // 196 * 256 padded rows (zeros)
#define NCLS  7
#define MPD4  12544      // MP/4

__device__ __forceinline__ u16 f2bf(float f) {          // RNE fp32 -> bf16
  unsigned u = __float_as_uint(f);
  u = (u + 0x7FFFu + ((u >> 16) & 1u)) >> 16;
  return (u16)u;
}
__device__ __forceinline__ float bf2f(u16 h) {
  return __uint_as_float(((unsigned)h) << 16);
}
__device__ __forceinline__ float gelu(float x) {
  return 0.5f * x * (1.0f + erff(x * 0.70710678118654752f));
}

__device__ __forceinline__ void load16_lds(const u16* g, u16* l) {
  __builtin_amdgcn_global_load_lds(
      (const __attribute__((address_space(1))) unsigned int*)(const void*)g,
      (__attribute__((address_space(3))) unsigned int*)(void*)l, 16, 0, 0);
}

#define MFMA_(a, b, c) __builtin_amdgcn_mfma_f32_16x16x32_bf16(a, b, c, 0, 0, 0)

// ------------------------- fp32 -> bf16 convert (features, +row zero-pad) --
__global__ __launch_bounds__(256) void k_convert(const float* __restrict__ src,
                                                 u16* __restrict__ dst,
                                                 int rows_total, int rows_valid) {
  const size_t total = (size_t)rows_total * DDIM / 8;
  const size_t stride = (size_t)gridDim.x * blockDim.x;
  for (size_t i = (size_t)blockIdx.x * blockDim.x + threadIdx.x; i < total; i += stride) {
    const size_t e = i * 8;
    const int row = (int)(e >> 10);
    u16x8 o = {0, 0, 0, 0, 0, 0, 0, 0};
    if (row < rows_valid) {
      const float4* p = (const float4*)(src + e);
      float4 f0 = p[0], f1 = p[1];
      o[0] = f2bf(f0.x); o[1] = f2bf(f0.y); o[2] = f2bf(f0.z); o[3] = f2bf(f0.w);
      o[4] = f2bf(f1.x); o[5] = f2bf(f1.y); o[6] = f2bf(f1.z); o[7] = f2bf(f1.w);
    }
    *(u16x8*)(dst + e) = o;
  }
}

// ------------------------- 3 weight matrices -> Wk, Wvq=concat(Wv,Wq) ------
__global__ __launch_bounds__(256) void k_convw(const float* __restrict__ kw,
                                               const float* __restrict__ vw,
                                               const float* __restrict__ qw,
                                               u16* __restrict__ Wk,
                                               u16* __restrict__ Wvq) {
  const int w = blockIdx.x >> 7;
  const int b = blockIdx.x & 127;
  const float* src = (w == 0) ? kw : (w == 1) ? vw : qw;
  u16* dst = (w == 0) ? Wk : (Wvq + (size_t)(w - 1) * DDIM * DDIM);
  for (int i = b * 256 + threadIdx.x; i < DDIM * DDIM / 8; i += 128 * 256) {
    const float4* p = (const float4*)(src + (size_t)i * 8);
    float4 f0 = p[0], f1 = p[1];
    u16x8 o;
    o[0] = f2bf(f0.x); o[1] = f2bf(f0.y); o[2] = f2bf(f0.z); o[3] = f2bf(f0.w);
    o[4] = f2bf(f1.x); o[5] = f2bf(f1.y); o[6] = f2bf(f1.z); o[7] = f2bf(f1.w);
    *(u16x8*)(dst + (size_t)i * 8) = o;
  }
}

// ------------------------- 256^2 phased GEMM (best measured) ---------------
// C[m,n] = sum_k A[m,k]*B[n,k].  M = 196 tiles; N-tiles = 1<<lnn; ldc given.
// LDS: A ring-3 (96 KiB) + B single (32 KiB). 4 single-barrier phases/tile;
// counted vmcnt(4) at the tile boundary (A(kt+2) stays in flight).
__global__ __launch_bounds__(512, 2) void k_gemm256(const u16* __restrict__ A,
                                                    const u16* __restrict__ Bw,
                                                    u16* __restrict__ C,
                                                    int lnn, int ldc) {
  extern __shared__ __align__(16) u16 smem[];
  u16* Abase = smem;                 // [3][2][8192]
  u16* Bbase = smem + 49152;         // [2][8192]
  const int tid  = threadIdx.x;
  const int lane = tid & 63;
  const int wid  = tid >> 6;
  const int wr = wid >> 2;           // 0..1  : A half (128 rows)
  const int wc = wid & 3;            // 0..3  : 64-col group
  const int bh = wc >> 1;            // B half this wave reads
  const int bl = (wc & 1) * 64;      // local n-row base within B half
  const int fr = lane & 15;
  const int T  = lane >> 4;
  const int cpx = gridDim.x >> 3;                              // nwg % 8 == 0
  const int v  = (blockIdx.x & 7) * cpx + (blockIdx.x >> 3);
  const int m0 = (v >> lnn) * 256;
  const int n0 = (v & ((1 << lnn) - 1)) * 256;

  f32x4 acc[8][4] = {};

#define STAGE_A(KT, BB) do {                                                   \
    _Pragma("unroll") for (int h_ = 0; h_ < 2; ++h_)                           \
      _Pragma("unroll") for (int l_ = 0; l_ < 2; ++l_) {                       \
        const int s_ = l_ * 512 + tid;                                         \
        const int r_ = s_ >> 3;                                                \
        const int c_ = (s_ & 7) ^ (r_ & 7);                                    \
        load16_lds(A + (size_t)(m0 + h_ * 128 + r_) * DDIM + (KT) * 64 + c_ * 8, \
                   Abase + (BB) * 16384 + h_ * 8192 + s_ * 8);                 \
      } } while (0)

#define STAGE_B(KT) do {                                                       \
    _Pragma("unroll") for (int h_ = 0; h_ < 2; ++h_)                           \
      _Pragma("unroll") for (int l_ = 0; l_ < 2; ++l_) {                       \
        const int s_ = l_ * 512 + tid;                                         \
        const int r_ = s_ >> 3;                                                \
        const int c_ = (s_ & 7) ^ (r_ & 7);                                    \
        load16_lds(Bw + (size_t)(n0 + h_ * 128 + r_) * DDIM + (KT) * 64 + c_ * 8, \
                   Bbase + h_ * 8192 + s_ * 8);                                \
      } } while (0)

#define PHASE_A(p) do {                                                        \
    bf16x8 afr[4];                                                             \
    _Pragma("unroll") for (int ks = 0; ks < 2; ++ks)                           \
      _Pragma("unroll") for (int ii = 0; ii < 2; ++ii) {                       \
        const int R = ((p) * 2 + ii) * 16 + fr;                                \
        afr[ks * 2 + ii] = *(const bf16x8*)&Ap[R * 64 + (((ks * 4 + T) ^ (R & 7)) << 3)]; \
      }                                                                        \
    __builtin_amdgcn_s_setprio(1);                                             \
    _Pragma("unroll") for (int ks = 0; ks < 2; ++ks)                           \
      _Pragma("unroll") for (int ii = 0; ii < 2; ++ii)                         \
        _Pragma("unroll") for (int j = 0; j < 4; ++j)                          \
          acc[(p) * 2 + ii][j] = MFMA_(afr[ks * 2 + ii], bfr[ks * 4 + j],      \
                                       acc[(p) * 2 + ii][j]);                  \
    __builtin_amdgcn_s_setprio(0);                                             \
  } while (0)

#define BARP() asm volatile("s_barrier" ::: "memory")

  // prologue: A(0)->slot0, B(0), A(1)->slot1 LAST; counted wait leaves A(1)
  STAGE_A(0, 0);
  STAGE_B(0);
  STAGE_A(1, 1);
  asm volatile("s_waitcnt vmcnt(4)\n\ts_barrier" ::: "memory");

  for (int kt = 0; kt < 16; ++kt) {
    const u16* Ap = Abase + (kt % 3) * 16384 + wr * 8192;
    const u16* Bp = Bbase + bh * 8192;
    bf16x8 bfr[8];
    // PH1: read all B-frags (B buffer dead afterwards) + A rows 0-1
#pragma unroll
    for (int ks = 0; ks < 2; ++ks)
#pragma unroll
      for (int j = 0; j < 4; ++j) {
        const int R = bl + j * 16 + fr;
        bfr[ks * 4 + j] = *(const bf16x8*)&Bp[R * 64 + (((ks * 4 + T) ^ (R & 7)) << 3)];
      }
    PHASE_A(0);
    BARP();
    // PH2: restage the single B buffer with B(kt+1)
    if (kt < 15) STAGE_B(kt + 1);
    PHASE_A(1);
    BARP();
    // PH3: stage A(kt+2) into ring slot (kt+2)%3 (dead since iter kt-1)
    if (kt < 14) STAGE_A(kt + 2, (kt + 2) % 3);
    PHASE_A(2);
    BARP();
    // PH4: counted wait — drain A(kt+1)+B(kt+1), leave A(kt+2) in flight
    PHASE_A(3);
    if (kt < 14)
      asm volatile("s_waitcnt vmcnt(4)\n\ts_barrier" ::: "memory");
    else if (kt == 14)
      asm volatile("s_waitcnt vmcnt(0)\n\ts_barrier" ::: "memory");
  }
#undef STAGE_A
#undef STAGE_B
#undef PHASE_A
#undef BARP

  // epilogue: C write
#pragma unroll
  for (int i = 0; i < 8; ++i)
#pragma unroll
    for (int j = 0; j < 4; ++j) {
      const size_t base = (size_t)(m0 + wr * 128 + i * 16 + T * 4) * ldc
                        + (n0 + wc * 64 + j * 16 + fr);
#pragma unroll
      for (int r = 0; r < 4; ++r)
        C[base + (size_t)r * ldc] = f2bf(acc[i][j][r]);
    }
}

// ------------------------- bias + LN + GELU for K (zero-pads rows) ---------
__global__ __launch_bounds__(256) void k_ln_k(const u16* __restrict__ h,
                                              const float* __restrict__ bias,
                                              const float* __restrict__ g,
                                              const float* __restrict__ beta,
                                              u16* __restrict__ out) {
  const int lane = threadIdx.x & 63;
  const int row = blockIdx.x * 4 + (threadIdx.x >> 6);
  const int c0 = lane * 8;
  u16x8* op0 = (u16x8*)(out + (size_t)row * DDIM + c0);
  u16x8* op1 = (u16x8*)(out + (size_t)row * DDIM + 512 + c0);
  if (row >= NROWS) {
    u16x8 z = {0, 0, 0, 0, 0, 0, 0, 0};
    *op0 = z; *op1 = z;
    return;
  }
  u16x8 h0 = *(const u16x8*)(h + (size_t)row * DDIM + c0);
  u16x8 h1 = *(const u16x8*)(h + (size_t)row * DDIM + 512 + c0);
  float4 a0 = *(const float4*)(bias + c0), a1 = *(const float4*)(bias + c0 + 4);
  float4 a2 = *(const float4*)(bias + 512 + c0), a3 = *(const float4*)(bias + 512 + c0 + 4);
  const float ba[8] = {a0.x, a0.y, a0.z, a0.w, a1.x, a1.y, a1.z, a1.w};
  const float bb[8] = {a2.x, a2.y, a2.z, a2.w, a3.x, a3.y, a3.z, a3.w};
  float v0[8], v1[8];
  float s1 = 0.f, s2 = 0.f;
#pragma unroll
  for (int e = 0; e < 8; ++e) {
    v0[e] = bf2f(h0[e]) + ba[e];
    v1[e] = bf2f(h1[e]) + bb[e];
    s1 += v0[e] + v1[e];
    s2 += v0[e] * v0[e] + v1[e] * v1[e];
  }
#pragma unroll
  for (int m = 1; m < 64; m <<= 1) {
    s1 += __shfl_xor(s1, m, 64);
    s2 += __shfl_xor(s2, m, 64);
  }
  const float mu = s1 * (1.0f / 1024.0f);
  const float var = s2 * (1.0f / 1024.0f) - mu * mu;
  const float rs = rsqrtf(var + 1e-5f);
  float4 g0 = *(const float4*)(g + c0), g1 = *(const float4*)(g + c0 + 4);
  float4 g2 = *(const float4*)(g + 512 + c0), g3 = *(const float4*)(g + 512 + c0 + 4);
  float4 t0 = *(const float4*)(beta + c0), t1 = *(const float4*)(beta + c0 + 4);
  float4 t2 = *(const float4*)(beta + 512 + c0), t3 = *(const float4*)(beta + 512 + c0 + 4);
  const float ga[8] = {g0.x, g0.y, g0.z, g0.w, g1.x, g1.y, g1.z, g1.w};
  const float gb[8] = {g2.x, g2.y, g2.z, g2.w, g3.x, g3.y, g3.z, g3.w};
  const float ta[8] = {t0.x, t0.y, t0.z, t0.w, t1.x, t1.y, t1.z, t1.w};
  const float tb[8] = {t2.x, t2.y, t2.z, t2.w, t3.x, t3.y, t3.z, t3.w};
  u16x8 o0, o1;
#pragma unroll
  for (int e = 0; e < 8; ++e) {
    o0[e] = f2bf(gelu((v0[e] - mu) * rs * ga[e] + ta[e]));
    o1[e] = f2bf(gelu((v1[e] - mu) * rs * gb[e] + tb[e]));
  }
  *op0 = o0; *op1 = o1;
}

// ------------------------- q_max from HbVQ rows (fin of argmax inside) -----
__global__ __launch_bounds__(64) void k_qmax2(const float* __restrict__ argv,
                                              const int* __restrict__ argi,
                                              const u16* __restrict__ hvq,
                                              const float* __restrict__ qb,
                                              const float* __restrict__ qg,
                                              const float* __restrict__ qbeta,
                                              u16* __restrict__ qm) {
  const int j = blockIdx.x;
  const int lane = threadIdx.x;
  float bv = -3.4e38f; int bi = 0x7fffffff;
  for (int p = lane; p < 128; p += 64) {
    const float v = argv[p * NCLS + j];
    const int   i = argi[p * NCLS + j];
    if (v > bv || (v == bv && i < bi)) { bv = v; bi = i; }
  }
#pragma unroll
  for (int m = 1; m < 64; m <<= 1) {
    const float ov = __shfl_xor(bv, m, 64);
    const int   oi = __shfl_xor(bi, m, 64);
    if (ov > bv || (ov == bv && oi < bi)) { bv = ov; bi = oi; }
  }
  const int row = bi;
  const int c0 = lane * 8;
  const u16* hp = hvq + (size_t)row * 2048 + DDIM;      // Q-half
  u16x8 h0 = *(const u16x8*)(hp + c0);
  u16x8 h1 = *(const u16x8*)(hp + 512 + c0);
  float v0[8], v1[8];
  float s1 = 0.f, s2 = 0.f;
#pragma unroll
  for (int e = 0; e < 8; ++e) {
    v0[e] = bf2f(h0[e]) + qb[c0 + e];
    v1[e] = bf2f(h1[e]) + qb[512 + c0 + e];
    s1 += v0[e] + v1[e];
    s2 += v0[e] * v0[e] + v1[e] * v1[e];
  }
#pragma unroll
  for (int m = 1; m < 64; m <<= 1) {
    s1 += __shfl_xor(s1, m, 64);
    s2 += __shfl_xor(s2, m, 64);
  }
  const float mu = s1 * (1.0f / 1024.0f);
  const float var = s2 * (1.0f / 1024.0f) - mu * mu;
  const float rs = rsqrtf(var + 1e-5f);
  u16x8 o0, o1;
#pragma unroll
  for (int e = 0; e < 8; ++e) {
    o0[e] = f2bf(gelu((v0[e] - mu) * rs * qg[c0 + e] + qbeta[c0 + e]));
    o1[e] = f2bf(gelu((v1[e] - mu) * rs * qg[512 + c0 + e] + qbeta[512 + c0 + e]));
  }
  *(u16x8*)(qm + (size_t)j * DDIM + c0) = o0;
  *(u16x8*)(qm + (size_t)j * DDIM + 512 + c0) = o1;
}

// ------------------------- merged V/Q LN; Q-half emits logits only ---------
__global__ __launch_bounds__(256) void k_ln_vq(const u16* __restrict__ h,
                                               const float* __restrict__ v_b,
                                               const float* __restrict__ v_g,
                                               const float* __restrict__ v_beta,
                                               const float* __restrict__ q_b,
                                               const float* __restrict__ q_g,
                                               const float* __restrict__ q_beta,
                                               const u16* __restrict__ qm,
                                               u16* __restrict__ V,
                                               float* __restrict__ logits) {
  __shared__ __align__(16) u16 sqm[NCLS * DDIM];        // 14 KB
  const int tid = threadIdx.x;
  const int lane = tid & 63;
  const int half = (blockIdx.x >= MPD4) ? 1 : 0;
  const int rb = half ? (blockIdx.x - MPD4) : blockIdx.x;
  const int row = rb * 4 + (tid >> 6);
  if (half) {
    for (int i = tid; i < NCLS * DDIM / 8; i += 256)
      *(u16x8*)&sqm[i * 8] = *(const u16x8*)&qm[i * 8];
    __syncthreads();
  }
  if (row >= NROWS) return;                             // no sync after this
  const float* bias = half ? q_b : v_b;
  const float* gain = half ? q_g : v_g;
  const float* bet  = half ? q_beta : v_beta;
  const int c0 = lane * 8;
  const u16* hp = h + (size_t)row * 2048 + (size_t)half * DDIM;
  u16x8 h0 = *(const u16x8*)(hp + c0);
  u16x8 h1 = *(const u16x8*)(hp + 512 + c0);
  float4 a0 = *(const float4*)(bias + c0), a1 = *(const float4*)(bias + c0 + 4);
  float4 a2 = *(const float4*)(bias + 512 + c0), a3 = *(const float4*)(bias + 512 + c0 + 4);
  const float ba[8] = {a0.x, a0.y, a0.z, a0.w, a1.x, a1.y, a1.z, a1.w};
  const float bb[8] = {a2.x, a2.y, a2.z, a2.w, a3.x, a3.y, a3.z, a3.w};
  float v0[8], v1[8];
  float s1 = 0.f, s2 = 0.f;
#pragma unroll
  for (int e = 0; e < 8; ++e) {
    v0[e] = bf2f(h0[e]) + ba[e];
    v1[e] = bf2f(h1[e]) + bb[e];
    s1 += v0[e] + v1[e];
    s2 += v0[e] * v0[e] + v1[e] * v1[e];
  }
#pragma unroll
  for (int m = 1; m < 64; m <<= 1) {
    s1 += __shfl_xor(s1, m, 64);
    s2 += __shfl_xor(s2, m, 64);
  }
  const float mu = s1 * (1.0f / 1024.0f);
  const float var = s2 * (1.0f / 1024.0f) - mu * mu;
  const float rs = rsqrtf(var + 1e-5f);
  float4 g0 = *(const float4*)(gain + c0), g1 = *(const float4*)(gain + c0 + 4);
  float4 g2 = *(const float4*)(gain + 512 + c0), g3 = *(const float4*)(gain + 512 + c0 + 4);
  float4 t0 = *(const float4*)(bet + c0), t1 = *(const float4*)(bet + c0 + 4);
  float4 t2 = *(const float4*)(bet + 512 + c0), t3 = *(const float4*)(bet + 512 + c0 + 4);
  const float ga[8] = {g0.x, g0.y, g0.z, g0.w, g1.x, g1.y, g1.z, g1.w};
  const float gb[8] = {g2.x, g2.y, g2.z, g2.w, g3.x, g3.y, g3.z, g3.w};
  const float ta[8] = {t0.x, t0.y, t0.z, t0.w, t1.x, t1.y, t1.z, t1.w};
  const float tb[8] = {t2.x, t2.y, t2.z, t2.w, t3.x, t3.y, t3.z, t3.w};
  float y0[8], y1[8];
#pragma unroll
  for (int e = 0; e < 8; ++e) {
    y0[e] = gelu((v0[e] - mu) * rs * ga[e] + ta[e]);
    y1[e] = gelu((v1[e] - mu) * rs * gb[e] + tb[e]);
  }
  if (half == 0) {
    u16x8 o0, o1;
#pragma unroll
    for (int e = 0; e < 8; ++e) { o0[e] = f2bf(y0[e]); o1[e] = f2bf(y1[e]); }
    *(u16x8*)(V + (size_t)row * DDIM + c0) = o0;
    *(u16x8*)(V + (size_t)row * DDIM + 512 + c0) = o1;
  } else {
#pragma unroll
    for (int j = 0; j < NCLS; ++j) {
      u16x8 m0 = *(const u16x8*)&sqm[j * DDIM + c0];
      u16x8 m1 = *(const u16x8*)&sqm[j * DDIM + 512 + c0];
      float p = 0.f;
#pragma unroll
      for (int e = 0; e < 8; ++e) p += y0[e] * bf2f(m0[e]) + y1[e] * bf2f(m1[e]);
#pragma unroll
      for (int m = 1; m < 64; m <<= 1) p += __shfl_xor(p, m, 64);
      if (lane == 0) logits[(size_t)row * NCLS + j] = p * 0.03125f;
    }
  }
}

// ------------------------- argmax partials (first-index) -------------------
__global__ __launch_bounds__(256) void k_arg1(const float* __restrict__ c,
                                              float* __restrict__ pv,
                                              int* __restrict__ pi) {
  __shared__ float sv[256 * NCLS];
  __shared__ int   si[256 * NCLS];
  const int t = threadIdx.x;
  float bv[NCLS]; int bi[NCLS];
#pragma unroll
  for (int j = 0; j < NCLS; ++j) { bv[j] = -3.4e38f; bi[j] = 0x7fffffff; }
  for (int n = blockIdx.x * 256 + t; n < NROWS; n += 128 * 256) {
#pragma unroll
    for (int j = 0; j < NCLS; ++j) {
      const float v = c[(size_t)n * NCLS + j];
      if (v > bv[j]) { bv[j] = v; bi[j] = n; }
    }
  }
#pragma unroll
  for (int j = 0; j < NCLS; ++j) { sv[t * NCLS + j] = bv[j]; si[t * NCLS + j] = bi[j]; }
  __syncthreads();
  for (int s = 128; s > 0; s >>= 1) {
    if (t < s) {
#pragma unroll
      for (int j = 0; j < NCLS; ++j) {
        const float v2 = sv[(t + s) * NCLS + j]; const int i2 = si[(t + s) * NCLS + j];
        const float v1 = sv[t * NCLS + j];       const int i1 = si[t * NCLS + j];
        if (v2 > v1 || (v2 == v1 && i2 < i1)) { sv[t * NCLS + j] = v2; si[t * NCLS + j] = i2; }
      }
    }
    __syncthreads();
  }
  if (t < NCLS) { pv[blockIdx.x * NCLS + t] = sv[t]; pi[blockIdx.x * NCLS + t] = si[t]; }
}

// ------------------------- one-pass softmax partials per block -------------
__global__ __launch_bounds__(256) void k_softpart(const float* __restrict__ logits,
                                                  float* __restrict__ Pm,
                                                  float* __restrict__ Ps) {
  __shared__ float sm[256 * NCLS];
  const int t = threadIdx.x;
  float m[NCLS];
#pragma unroll
  for (int j = 0; j < NCLS; ++j) m[j] = -3.4e38f;
  for (int n = blockIdx.x * 256 + t; n < NROWS; n += 128 * 256)
#pragma unroll
    for (int j = 0; j < NCLS; ++j) m[j] = fmaxf(m[j], logits[(size_t)n * NCLS + j]);
#pragma unroll
  for (int j = 0; j < NCLS; ++j) sm[t * NCLS + j] = m[j];
  __syncthreads();
  for (int s = 128; s > 0; s >>= 1) {
    if (t < s)
#pragma unroll
      for (int j = 0; j < NCLS; ++j)
        sm[t * NCLS + j] = fmaxf(sm[t * NCLS + j], sm[(t + s) * NCLS + j]);
    __syncthreads();
  }
  float mloc[NCLS];
#pragma unroll
  for (int j = 0; j < NCLS; ++j) mloc[j] = sm[j];
  __syncthreads();
  float s[NCLS];
#pragma unroll
  for (int j = 0; j < NCLS; ++j) s[j] = 0.f;
  for (int n = blockIdx.x * 256 + t; n < NROWS; n += 128 * 256)
#pragma unroll
    for (int j = 0; j < NCLS; ++j) s[j] += expf(logits[(size_t)n * NCLS + j] - mloc[j]);
#pragma unroll
  for (int j = 0; j < NCLS; ++j) sm[t * NCLS + j] = s[j];
  __syncthreads();
  for (int st = 128; st > 0; st >>= 1) {
    if (t < st)
#pragma unroll
      for (int j = 0; j < NCLS; ++j) sm[t * NCLS + j] += sm[(t + st) * NCLS + j];
    __syncthreads();
  }
  if (t < NCLS) { Pm[blockIdx.x * NCLS + t] = mloc[t]; Ps[blockIdx.x * NCLS + t] = sm[t]; }
}

// ------------------------- B-partials = A^T V, fused A-write + rescale-fin -
__global__ __launch_bounds__(256) void k_bpart(const float* __restrict__ logits,
                                               const float* __restrict__ Pm,
                                               const float* __restrict__ Ps,
                                               const u16* __restrict__ V,
                                               float* __restrict__ Aout,
                                               float* __restrict__ Pb) {
  __shared__ float sA[98 * NCLS];
  __shared__ float sM[NCLS], sR[NCLS];
  const int t = threadIdx.x;
  if (t < NCLS) {
    float M = -3.4e38f;
    for (int b = 0; b < 128; ++b) M = fmaxf(M, Pm[b * NCLS + t]);
    float S = 0.f;
    for (int b = 0; b < 128; ++b) S += Ps[b * NCLS + t] * expf(Pm[b * NCLS + t] - M);
    sM[t] = M; sR[t] = 1.0f / S;
  }
  __syncthreads();
  const int n0 = blockIdx.x * 98;
  int cnt = NROWS - n0;
  cnt = cnt < 0 ? 0 : (cnt > 98 ? 98 : cnt);
  for (int idx = t; idx < cnt * NCLS; idx += 256) {
    const int j = idx % NCLS;
    const float a = expf(logits[(size_t)n0 * NCLS + idx] - sM[j]) * sR[j];
    sA[idx] = a;
    Aout[(size_t)n0 * NCLS + idx] = a;
  }
  __syncthreads();
  float acc[NCLS][4] = {};
  for (int r = 0; r < cnt; ++r) {
    u16x4 vv = *(const u16x4*)&V[(size_t)(n0 + r) * DDIM + t * 4];
    const float f0 = bf2f(vv[0]), f1 = bf2f(vv[1]), f2 = bf2f(vv[2]), f3 = bf2f(vv[3]);
#pragma unroll
    for (int j = 0; j < NCLS; ++j) {
      const float a = sA[r * NCLS + j];
      acc[j][0] += a * f0; acc[j][1] += a * f1; acc[j][2] += a * f2; acc[j][3] += a * f3;
    }
  }
#pragma unroll
  for (int j = 0; j < NCLS; ++j) {
    f32x4 o = {acc[j][0], acc[j][1], acc[j][2], acc[j][3]};
    *(f32x4*)&Pb[((size_t)blockIdx.x * NCLS + j) * DDIM + t * 4] = o;
  }
}

__global__ void k_bred(const float* __restrict__ Pb, float* __restrict__ Bout) {
  const int idx = blockIdx.x * 256 + threadIdx.x;
  if (idx >= NCLS * DDIM) return;
  float s = 0.f;
  for (int p = 0; p < 512; ++p) s += Pb[(size_t)p * NCLS * DDIM + idx];
  Bout[idx] = s;
}

// ------------------------- C[o] = <B, head_w[o]> + head_b[o] ---------------
__global__ __launch_bounds__(256) void k_head(const float* __restrict__ Bmat,
                                              const float* __restrict__ hw,
                                              const float* __restrict__ hb,
                                              float* __restrict__ Cout) {
  const int o = blockIdx.x, t = threadIdx.x;
  float p = 0.f;
  for (int idx = t; idx < NCLS * DDIM; idx += 256)
    p += Bmat[idx] * hw[(size_t)o * NCLS * DDIM + idx];
#pragma unroll
  for (int m = 1; m < 64; m <<= 1) p += __shfl_xor(p, m, 64);
  __shared__ float w[4];
  if ((t & 63) == 0) w[t >> 6] = p;
  __syncthreads();
  if (t == 0) Cout[o] = w[0] + w[1] + w[2] + w[3] + hb[o];
}

// ---------------------------------------------------------------------------
extern "C" void kernel_launch(void* const* d_in, const int* in_sizes, int n_in,
                              void* d_out, int out_size, void* d_ws, size_t ws_size,
                              hipStream_t stream) {
  const float* features   = (const float*)d_in[0];
  const float* c_in       = (const float*)d_in[1];
  const float* key_w      = (const float*)d_in[2];
  const float* key_b      = (const float*)d_in[3];
  const float* key_g      = (const float*)d_in[4];
  const float* key_beta   = (const float*)d_in[5];
  const float* query_w    = (const float*)d_in[6];
  const float* query_b    = (const float*)d_in[7];
  const float* query_g    = (const float*)d_in[8];
  const float* query_beta = (const float*)d_in[9];
  const float* value_w    = (const float*)d_in[10];
  const float* value_b    = (const float*)d_in[11];
  const float* value_g    = (const float*)d_in[12];
  const float* value_beta = (const float*)d_in[13];
  const float* head_w     = (const float*)d_in[14];
  const float* head_b     = (const float*)d_in[15];

  char* ws = (char*)d_ws;
  const size_t SZB = (size_t)MP * DDIM * 2;             // 102,760,448 B
  u16* Xb   = (u16*)ws;                                 // [MP,1024] features bf16
  u16* HbK  = (u16*)(ws + SZB);                         // [MP,1024] pre-LN K
  u16* HbVQ = Xb;                                       // [MP,2048] aliases Xb|HbK (both dead)
  u16* Kb   = (u16*)(ws + 2 * SZB);                     // [MP,1024]
  u16* Vb   = Kb;                                       // reuse after VQ-GEMM
  size_t off = 3 * SZB;
  u16* Wk  = (u16*)(ws + off); off += (size_t)DDIM * DDIM * 2;
  u16* Wvq = (u16*)(ws + off); off += (size_t)2 * DDIM * DDIM * 2;
  float* logits = (float*)(ws + off); off += ((size_t)NROWS * NCLS * 4 + 255) & ~(size_t)255;
  float* Pb  = (float*)(ws + off); off += (size_t)512 * NCLS * DDIM * 4;
  u16* qm    = (u16*)(ws + off); off += ((size_t)NCLS * DDIM * 2 + 255) & ~(size_t)255;
  float* Pmax = (float*)(ws + off); off += ((size_t)128 * NCLS * 4 + 255) & ~(size_t)255;
  float* Psum = (float*)(ws + off); off += ((size_t)128 * NCLS * 4 + 255) & ~(size_t)255;
  float* argv = (float*)(ws + off); off += ((size_t)128 * NCLS * 4 + 255) & ~(size_t)255;
  int*   argi = (int*)  (ws + off); off += ((size_t)128 * NCLS * 4 + 255) & ~(size_t)255;

  float* Cout = (float*)d_out;                          // [7]
  float* Aout = Cout + NCLS;                            // [50000,7]
  float* Bout = Aout + (size_t)NROWS * NCLS;            // [7,1024]

  // argmax partials + dtype converts
  k_arg1<<<128, 256, 0, stream>>>(c_in, argv, argi);
  k_convw<<<384, 256, 0, stream>>>(key_w, value_w, query_w, Wk, Wvq);
  k_convert<<<2048, 256, 0, stream>>>(features, Xb, MP, NROWS);

  // K chain: 256^2 phased GEMM (196 x 4 tiles), then LN (zero-pads to MP)
  k_gemm256<<<784, 512, 131072, stream>>>(Xb, Wk, HbK, 2, 1024);
  k_ln_k<<<MPD4, 256, 0, stream>>>(HbK, key_b, key_g, key_beta, Kb);

  // merged V|Q GEMM: 256^2 phased kernel (196 x 8 tiles); HbVQ aliases Xb|HbK
  k_gemm256<<<1568, 512, 131072, stream>>>(Kb, Wvq, HbVQ, 3, 2048);
  k_qmax2<<<NCLS, 64, 0, stream>>>(argv, argi, HbVQ, query_b, query_g, query_beta, qm);
  k_ln_vq<<<2 * MPD4, 256, 0, stream>>>(HbVQ, value_b, value_g, value_beta,
                                        query_b, query_g, query_beta, qm, Vb, logits);

  // softmax over axis 0: one-pass partials, rescale-fin in consumer
  k_softpart<<<128, 256, 0, stream>>>(logits, Pmax, Psum);

  // B = A^T V (A materialized on the fly), head contraction
  k_bpart<<<512, 256, 0, stream>>>(logits, Pmax, Psum, Vb, Aout, Pb);
  k_bred<<<28, 256, 0, stream>>>(Pb, Bout);
  k_head<<<NCLS, 256, 0, stream>>>(Bout, head_w, head_b, Cout);
}